// Round 16
// baseline (8108.759 us; speedup 1.0000x reference)
//
#include <hip/hip_runtime.h>
#include <math.h>

#define NNODES 100000
#define NEDGES 800000
#define L 128
#define NBSCAN ((NNODES + 255) / 256)   // 391 scan blocks

typedef unsigned short u16;
typedef unsigned int u32;
typedef unsigned short ushort8 __attribute__((ext_vector_type(8)));
typedef _Float16 f16x8 __attribute__((ext_vector_type(8)));
typedef __attribute__((ext_vector_type(4))) float f32x4;

// ---- conversions -----------------------------------------------------------
static __device__ __forceinline__ float h2f(u16 u) {       // fp16 -> f32
    _Float16 h;
    __builtin_memcpy(&h, &u, 2);
    return (float)h;
}
static __device__ __forceinline__ u16 f2h(float x) {       // f32 -> fp16 RNE
    _Float16 h = (_Float16)x;
    u16 u;
    __builtin_memcpy(&u, &h, 2);
    return u;
}
static __device__ __forceinline__ void load8h(const u16* p, float* d) {
    ushort8 v = *(const ushort8*)p;
    #pragma unroll
    for (int k = 0; k < 8; k++) d[k] = h2f(v[k]);
}
// HW packed fp16x2 atomic add (gfx90a+), no memory clobber (nothing here
// reads aggr; clobber would serialize the epilogue).
static __device__ __forceinline__ void atomic_pk_add_f16(u16* addr, u32 data) {
    asm volatile("global_atomic_pk_add_f16 %0, %1, off" :: "v"(addr), "v"(data));
}

// ---------------------------------------------------------------------------
__global__ __launch_bounds__(256) void zero_kernel(uint4* p, int n) {
    int i = blockIdx.x * 256 + threadIdx.x;
    if (i < n) p[i] = make_uint4(0u, 0u, 0u, 0u);
}

__global__ __launch_bounds__(256) void diag_kernel(float* out, int n, float val) {
    int i = blockIdx.x * 256 + threadIdx.x;
    if (i < n) out[i] = val;
}

// ---------------------------------------------------------------------------
// Counting sort of edges by receiver: counts -> scan -> scatter.
// ---------------------------------------------------------------------------
__global__ __launch_bounds__(256) void count_kernel(
    const int* __restrict__ receivers, u32* __restrict__ counts)
{
    int e = blockIdx.x * 256 + threadIdx.x;
    if (e < NEDGES) atomicAdd(&counts[receivers[e]], 1u);
}

__global__ __launch_bounds__(256) void scan_block_kernel(
    const u32* __restrict__ counts, u32* __restrict__ offsets,
    u32* __restrict__ partials)
{
    __shared__ u32 sh[256];
    int i = blockIdx.x * 256 + threadIdx.x;
    u32 c = (i < NNODES) ? counts[i] : 0u;
    sh[threadIdx.x] = c;
    __syncthreads();
    #pragma unroll
    for (int d = 1; d < 256; d <<= 1) {
        u32 v = (threadIdx.x >= d) ? sh[threadIdx.x - d] : 0u;
        __syncthreads();
        sh[threadIdx.x] += v;
        __syncthreads();
    }
    if (i < NNODES) offsets[i] = sh[threadIdx.x] - c;   // excl within block
    if (threadIdx.x == 255) partials[blockIdx.x] = sh[255];
}

__global__ __launch_bounds__(512) void scan_partials_kernel(u32* __restrict__ partials)
{
    __shared__ u32 sh[512];
    int x = threadIdx.x;
    u32 c = (x < NBSCAN) ? partials[x] : 0u;
    sh[x] = c;
    __syncthreads();
    #pragma unroll
    for (int d = 1; d < 512; d <<= 1) {
        u32 v = (x >= d) ? sh[x - d] : 0u;
        __syncthreads();
        sh[x] += v;
        __syncthreads();
    }
    if (x < NBSCAN) partials[x] = sh[x] - c;            // exclusive
}

__global__ __launch_bounds__(256) void add_offsets_kernel(
    u32* __restrict__ offsets, const u32* __restrict__ partials,
    u32* __restrict__ cursor)
{
    int i = blockIdx.x * 256 + threadIdx.x;
    if (i < NNODES) {
        u32 v = offsets[i] + partials[blockIdx.x];
        offsets[i] = v;
        cursor[i] = v;
    }
}

__global__ __launch_bounds__(256) void scatter_kernel(
    const int* __restrict__ senders, const int* __restrict__ receivers,
    u32* __restrict__ cursor, int* __restrict__ ssorted, int* __restrict__ rsorted)
{
    int e = blockIdx.x * 256 + threadIdx.x;
    if (e < NEDGES) {
        int r = receivers[e];
        u32 pos = atomicAdd(&cursor[r], 1u);
        ssorted[pos] = senders[e];
        rsorted[pos] = r;
    }
}

// ---------------------------------------------------------------------------
// Weight pre-pack into MFMA B-fragment order, single fp16.
// ---------------------------------------------------------------------------
__global__ __launch_bounds__(256) void pack_weights_kernel(
    const float* __restrict__ src, u16* __restrict__ dst, int K, int nsteps)
{
    int idx = blockIdx.x * 256 + threadIdx.x;
    int nkk = K >> 5;
    int total = nsteps * 8 * nkk * 64;
    if (idx >= total) return;
    int lane = idx & 63;
    int rest = idx >> 6;
    int kk = rest % nkk; rest /= nkk;
    int nb = rest & 7;
    int s = rest >> 3;
    int c15 = lane & 15, gg = lane >> 4;
    const float* w = src + (size_t)s * K * 128;
    u16 out[8];
    #pragma unroll
    for (int j = 0; j < 8; j++) {
        int k = kk * 32 + gg * 8 + j;
        out[j] = f2h(w[(size_t)k * 128 + nb * 16 + c15]);
    }
    *(ushort8*)(dst + (size_t)idx * 8) = *(ushort8*)out;
}

// pack edge-encoder layer1 (7x128), K padded to 32 with zero rows
__global__ __launch_bounds__(256) void pack_ee1_kernel(
    const float* __restrict__ src, u16* __restrict__ dst)
{
    int idx = blockIdx.x * 256 + threadIdx.x;
    if (idx >= 8 * 64) return;
    int lane = idx & 63, nb = idx >> 6;
    int c15 = lane & 15, gg = lane >> 4;
    u16 out[8];
    #pragma unroll
    for (int j = 0; j < 8; j++) {
        int k = gg * 8 + j;
        out[j] = (k < 7) ? f2h(src[(size_t)k * 128 + nb * 16 + c15]) : (u16)0;
    }
    *(ushort8*)(dst + (size_t)idx * 8) = *(ushort8*)out;
}

// ---------------------------------------------------------------------------
// Node encoder: feats(6) -> 128 -> 128 -> LN -> fp16 nl  (64 nodes / block)
// ---------------------------------------------------------------------------
__global__ __launch_bounds__(256) void node_encode_kernel(
    const float* __restrict__ pvf, const float* __restrict__ matD,
    const float* __restrict__ matX, const int* __restrict__ ntype,
    const float* __restrict__ nmean, const float* __restrict__ nstd,
    const float* __restrict__ w1, const float* __restrict__ b1,
    const float* __restrict__ w2, const float* __restrict__ b2,
    const float* __restrict__ g, const float* __restrict__ be,
    u16* __restrict__ nl)
{
    __shared__ float xs[64][8];
    __shared__ float h[64][132];
    const int t = threadIdx.x;
    const int base = blockIdx.x * 64;
    if (t < 64) {
        int n = base + t;
        if (n < NNODES) {
            int nt = ntype[n];
            float f[6];
            f[0] = pvf[n]; f[1] = matD[n]; f[2] = matX[n];
            f[3] = (nt == 0) ? 1.f : 0.f;
            f[4] = (nt == 1) ? 1.f : 0.f;
            f[5] = (nt == 2) ? 1.f : 0.f;
            #pragma unroll
            for (int k = 0; k < 6; k++) xs[t][k] = (f[k] - nmean[k]) / nstd[k];
        } else {
            #pragma unroll
            for (int k = 0; k < 6; k++) xs[t][k] = 0.f;
        }
    }
    __syncthreads();
    const int j = t & 127, half = t >> 7;
    for (int i = 0; i < 32; i++) {
        int e = half * 32 + i;
        float acc = b1[j];
        #pragma unroll
        for (int k = 0; k < 6; k++) acc += xs[e][k] * w1[k * L + j];
        h[e][j] = fmaxf(acc, 0.f);
    }
    __syncthreads();
    float acc2[32];
    #pragma unroll
    for (int i = 0; i < 32; i++) acc2[i] = b2[j];
    for (int k4 = 0; k4 < 32; k4++) {
        const float* wp = w2 + k4 * 4 * L + j;
        float wa = wp[0], wb = wp[L], wc = wp[2 * L], wd = wp[3 * L];
        #pragma unroll
        for (int i = 0; i < 32; i++) {
            const float4 xv = *(const float4*)&h[half * 32 + i][k4 * 4];
            acc2[i] += xv.x * wa + xv.y * wb + xv.z * wc + xv.w * wd;
        }
    }
    __syncthreads();
    #pragma unroll
    for (int i = 0; i < 32; i++) h[half * 32 + i][j] = fmaxf(acc2[i], 0.f);
    __syncthreads();
    {
        const int e = t >> 2, tg = t & 3;
        float sum = 0.f, sq = 0.f;
        #pragma unroll
        for (int jj = 0; jj < 32; jj++) { float v = h[e][tg * 32 + jj]; sum += v; sq += v * v; }
        sum += __shfl_xor(sum, 1); sq += __shfl_xor(sq, 1);
        sum += __shfl_xor(sum, 2); sq += __shfl_xor(sq, 2);
        float mu = sum * (1.f / 128.f);
        float rstd = rsqrtf(sq * (1.f / 128.f) - mu * mu + 1e-5f);
        int n = base + e;
        if (n < NNODES) {
            u32* nrow = (u32*)(nl + (size_t)n * L) + tg * 16;
            #pragma unroll
            for (int p = 0; p < 16; p++) {
                int f0 = tg * 32 + 2 * p;
                float v0 = (h[e][f0] - mu) * rstd * g[f0] + be[f0];
                float v1 = (h[e][f0 + 1] - mu) * rstd * g[f0 + 1] + be[f0 + 1];
                nrow[p] = (u32)f2h(v0) | ((u32)f2h(v1) << 16);
            }
        }
    }
}

// ---------------------------------------------------------------------------
// MFMA edge encoder (sorted edge space): feats(7, padded to K=32) -> 128
// -> 128 -> LN -> fp16 el.  256 edges/block, 4 waves, wave = 64 rows.
// ---------------------------------------------------------------------------
__global__ __launch_bounds__(256, 2) void edge_encode_kernel(
    const int* __restrict__ ssorted, const int* __restrict__ rsorted,
    const float* __restrict__ pvf, const float* __restrict__ mesh,
    const float* __restrict__ world,
    const float* __restrict__ emean, const float* __restrict__ estd,
    const u16* __restrict__ wp1, const float* __restrict__ b1,
    const u16* __restrict__ wp2, const float* __restrict__ b2,
    const float* __restrict__ gamma, const float* __restrict__ beta,
    u16* __restrict__ el)
{
    __shared__ __align__(16) u16 hbuf[4][2][4][64][8];   // 32 KB
    const int t = threadIdx.x;
    const int wid = t >> 6, lane = t & 63;
    const int c15 = lane & 15, g = lane >> 4;
    const int base = blockIdx.x * 256 + wid * 64;   // E % 256 == 0

    // A-fragments: only the g==0 k-chunk carries the 7 features (rest zero)
    f16x8 a[4];
    #pragma unroll
    for (int m = 0; m < 4; m++) {
        f16x8 v;
        #pragma unroll
        for (int k = 0; k < 8; k++) v[k] = (_Float16)0.f;
        if (g == 0) {
            int e = base + m * 16 + c15;
            int s = ssorted[e], r = rsorted[e];
            float rmx = mesh[s * 2] - mesh[r * 2];
            float rmy = mesh[s * 2 + 1] - mesh[r * 2 + 1];
            float dm = sqrtf(rmx * rmx + rmy * rmy);
            float rwx = world[s * 2] - world[r * 2];
            float rwy = world[s * 2 + 1] - world[r * 2 + 1];
            float dw = sqrtf(rwx * rwx + rwy * rwy);
            float pg = pvf[s] - pvf[r];
            float f[7] = {rmx, rmy, dm, rwx, rwy, dw, pg};
            #pragma unroll
            for (int k = 0; k < 7; k++)
                v[k] = (_Float16)((f[k] - emean[k]) / estd[k]);
        }
        a[m] = v;
    }

    // ---- layer 1: single k-step (K=32 padded) ----
    f32x4 acc[8][4];
    #pragma unroll
    for (int nb = 0; nb < 8; nb++) {
        float bv = b1[nb * 16 + c15];
        #pragma unroll
        for (int m = 0; m < 4; m++) acc[nb][m] = (f32x4){bv, bv, bv, bv};
    }
    #pragma unroll
    for (int nb = 0; nb < 8; nb++) {
        f16x8 b = *(const f16x8*)(wp1 + ((size_t)(nb * 64 + lane)) * 8);
        #pragma unroll
        for (int m = 0; m < 4; m++)
            acc[nb][m] = __builtin_amdgcn_mfma_f32_16x16x32_f16(a[m], b, acc[nb][m], 0, 0, 0);
    }

    // ---- layer 2 in m-pairs ----
    float gamv[8], btv[8];
    #pragma unroll
    for (int nb = 0; nb < 8; nb++) {
        gamv[nb] = gamma[nb * 16 + c15];
        btv[nb] = beta[nb * 16 + c15];
    }
    #pragma unroll
    for (int mp = 0; mp < 2; mp++) {
        #pragma unroll
        for (int ml = 0; ml < 2; ml++) {
            int m = mp * 2 + ml;
            #pragma unroll
            for (int nb = 0; nb < 8; nb++) {
                int kk2 = nb >> 1;
                int sub = ((nb & 1) << 1) | (c15 >> 3);
                int jj = c15 & 7;
                #pragma unroll
                for (int i = 0; i < 4; i++) {
                    float v = fmaxf(acc[nb][m][i], 0.f);
                    hbuf[wid][ml][kk2][g * 4 + i + 16 * sub][jj] = f2h(v);
                }
            }
        }
        f32x4 acc2[2][8];
        #pragma unroll
        for (int nb = 0; nb < 8; nb++) {
            float bv = b2[nb * 16 + c15];
            acc2[0][nb] = (f32x4){bv, bv, bv, bv};
            acc2[1][nb] = (f32x4){bv, bv, bv, bv};
        }
        #pragma unroll
        for (int kk = 0; kk < 4; kk++) {
            f16x8 a0 = *(const f16x8*)&hbuf[wid][0][kk][lane][0];
            f16x8 a1 = *(const f16x8*)&hbuf[wid][1][kk][lane][0];
            #pragma unroll
            for (int nb = 0; nb < 8; nb++) {
                f16x8 b = *(const f16x8*)(wp2 + ((size_t)(nb * 4 + kk) * 64 + lane) * 8);
                acc2[0][nb] = __builtin_amdgcn_mfma_f32_16x16x32_f16(a0, b, acc2[0][nb], 0, 0, 0);
                acc2[1][nb] = __builtin_amdgcn_mfma_f32_16x16x32_f16(a1, b, acc2[1][nb], 0, 0, 0);
            }
        }
        #pragma unroll
        for (int ml = 0; ml < 2; ml++) {
            float muv[4], rsv[4];
            #pragma unroll
            for (int i = 0; i < 4; i++) {
                float p = 0.f, q = 0.f;
                #pragma unroll
                for (int nb = 0; nb < 8; nb++) {
                    float v = fmaxf(acc2[ml][nb][i], 0.f);
                    acc2[ml][nb][i] = v;
                    p += v; q += v * v;
                }
                p += __shfl_xor(p, 1); q += __shfl_xor(q, 1);
                p += __shfl_xor(p, 2); q += __shfl_xor(q, 2);
                p += __shfl_xor(p, 4); q += __shfl_xor(q, 4);
                p += __shfl_xor(p, 8); q += __shfl_xor(q, 8);
                float mu = p * (1.f / 128.f);
                muv[i] = mu;
                rsv[i] = rsqrtf(q * (1.f / 128.f) - mu * mu + 1e-5f);
            }
            #pragma unroll
            for (int i = 0; i < 4; i++) {
                int erow = base + (mp * 2 + ml) * 16 + g * 4 + i;
                #pragma unroll
                for (int nb = 0; nb < 8; nb++) {
                    float v = (acc2[ml][nb][i] - muv[i]) * rsv[i] * gamv[nb] + btv[nb];
                    float pv = __shfl_xor(v, 1);
                    if (!(c15 & 1)) {
                        *(u32*)(el + (size_t)erow * L + nb * 16 + c15) =
                            (u32)f2h(v) | ((u32)f2h(pv) << 16);
                    }
                }
            }
        }
    }
}

// A-gather for edge layer-1, k-step nk (0..11), into ab[slot]
#define EDGE_LOAD_A(nk, slot)                                                     \
    {                                                                             \
        _Pragma("unroll")                                                         \
        for (int m = 0; m < 4; m++) {                                             \
            const u16* ap;                                                        \
            if ((nk) < 4)      ap = nl + (size_t)sA[m] * L + (nk) * 32 + g * 8;   \
            else if ((nk) < 8) ap = nl + (size_t)rA[m] * L + ((nk) - 4) * 32 + g * 8; \
            else               ap = el + (size_t)(base + m * 16 + c15) * L + ((nk) - 8) * 32 + g * 8; \
            ab[slot][m] = *(const f16x8*)ap;                                      \
        }                                                                         \
    }

#define NODE_LOAD_A(nk, slot)                                                     \
    {                                                                             \
        _Pragma("unroll")                                                         \
        for (int m = 0; m < 4; m++) {                                             \
            const u16* ap = ((nk) < 4) ? (nl + (size_t)rowL[m] * L + (nk) * 32 + g * 8) \
                                       : (aggr + (size_t)rowL[m] * L + ((nk) - 4) * 32 + g * 8); \
            ab[slot][m] = *(const f16x8*)ap;                                      \
        }                                                                         \
    }

// within-wave LDS RAW fence (no s_barrier: buffers are wave-private)
#define WAVE_LDS_FENCE()                                        \
    asm volatile("s_waitcnt lgkmcnt(0)" ::: "memory");          \
    __builtin_amdgcn_sched_barrier(0);

// ---------------------------------------------------------------------------
// fp16-MFMA GraphNetBlock edge update — BARRIER-FREE 1-wave blocks.
// B-fragments double-buffered in REGISTERS (prefetch 1 k-step, L2-resident
// weights shared by all blocks), A-prefetch 1 step; no s_barrier anywhere.
// 64 edges/block (1 wave). Sorted edge space; run-merged aggr atomics.
// ---------------------------------------------------------------------------
__global__ __launch_bounds__(64, 2) void edge_block_kernel(
    const int* __restrict__ ssorted, const int* __restrict__ rsorted,
    const u16* __restrict__ nl, u16* __restrict__ el, u16* __restrict__ aggr,
    const u16* __restrict__ wp1, const float* __restrict__ b1,
    const u16* __restrict__ wp2, const float* __restrict__ b2,
    const float* __restrict__ gamma, const float* __restrict__ beta)
{
    __shared__ __align__(16) u16 hbuf[2][4][64][8];   // 8 KB, wave-private
    const int lane = threadIdx.x & 63;
    const int c15 = lane & 15, g = lane >> 4;
    const int base = blockIdx.x * 64;   // E % 64 == 0

    int sA[4], rA[4];
    #pragma unroll
    for (int m = 0; m < 4; m++) {
        sA[m] = ssorted[base + m * 16 + c15];
        rA[m] = rsorted[base + m * 16 + c15];
    }

    // ---- layer 1: K = 384 (12 k-steps), M = 64, reg-dbuf B, no barriers ----
    f32x4 acc[8][4];
    #pragma unroll
    for (int nb = 0; nb < 8; nb++) {
        float bv = b1[nb * 16 + c15];
        #pragma unroll
        for (int m = 0; m < 4; m++) acc[nb][m] = (f32x4){bv, bv, bv, bv};
    }
    f16x8 ab[2][4];
    f16x8 bbuf[2][8];
    #pragma unroll
    for (int nb = 0; nb < 8; nb++)
        bbuf[0][nb] = *(const f16x8*)(wp1 + ((size_t)(nb * 12) * 64 + lane) * 8);
    EDGE_LOAD_A(0, 0);

    #pragma unroll
    for (int kk = 0; kk < 12; kk++) {
        if (kk < 11) {
            #pragma unroll
            for (int nb = 0; nb < 8; nb++)
                bbuf[(kk + 1) & 1][nb] =
                    *(const f16x8*)(wp1 + ((size_t)(nb * 12 + kk + 1) * 64 + lane) * 8);
            EDGE_LOAD_A(kk + 1, (kk + 1) & 1);
        }
        __builtin_amdgcn_s_setprio(1);
        #pragma unroll
        for (int nb = 0; nb < 8; nb++) {
            #pragma unroll
            for (int m = 0; m < 4; m++)
                acc[nb][m] = __builtin_amdgcn_mfma_f32_16x16x32_f16(
                    ab[kk & 1][m], bbuf[kk & 1][nb], acc[nb][m], 0, 0, 0);
        }
        __builtin_amdgcn_s_setprio(0);
    }

    // ---- layer 2 in m-pairs (B JIT from global/L2) ----
    float gamv[8], btv[8];
    #pragma unroll
    for (int nb = 0; nb < 8; nb++) {
        gamv[nb] = gamma[nb * 16 + c15];
        btv[nb] = beta[nb * 16 + c15];
    }
    #pragma unroll
    for (int mp = 0; mp < 2; mp++) {
        #pragma unroll
        for (int ml = 0; ml < 2; ml++) {
            int m = mp * 2 + ml;
            #pragma unroll
            for (int nb = 0; nb < 8; nb++) {
                int kk2 = nb >> 1;
                int sub = ((nb & 1) << 1) | (c15 >> 3);
                int jj = c15 & 7;
                #pragma unroll
                for (int i = 0; i < 4; i++) {
                    float v = fmaxf(acc[nb][m][i], 0.f);
                    hbuf[ml][kk2][g * 4 + i + 16 * sub][jj] = f2h(v);
                }
            }
        }
        WAVE_LDS_FENCE();
        f32x4 acc2[2][8];
        #pragma unroll
        for (int nb = 0; nb < 8; nb++) {
            float bv = b2[nb * 16 + c15];
            acc2[0][nb] = (f32x4){bv, bv, bv, bv};
            acc2[1][nb] = (f32x4){bv, bv, bv, bv};
        }
        __builtin_amdgcn_s_setprio(1);
        #pragma unroll
        for (int kk = 0; kk < 4; kk++) {
            f16x8 a0 = *(const f16x8*)&hbuf[0][kk][lane][0];
            f16x8 a1 = *(const f16x8*)&hbuf[1][kk][lane][0];
            #pragma unroll
            for (int nb = 0; nb < 8; nb++) {
                f16x8 b = *(const f16x8*)(wp2 + ((size_t)(nb * 4 + kk) * 64 + lane) * 8);
                acc2[0][nb] = __builtin_amdgcn_mfma_f32_16x16x32_f16(a0, b, acc2[0][nb], 0, 0, 0);
                acc2[1][nb] = __builtin_amdgcn_mfma_f32_16x16x32_f16(a1, b, acc2[1][nb], 0, 0, 0);
            }
        }
        __builtin_amdgcn_s_setprio(0);
        WAVE_LDS_FENCE();   // hbuf reads done before next mp overwrites
        // ---- relu + LN + residual + run-merged aggr atomics, per m ----
        #pragma unroll
        for (int ml = 0; ml < 2; ml++) {
            const int slot = mp * 2 + ml;
            float muv[4], rsv[4];
            #pragma unroll
            for (int i = 0; i < 4; i++) {
                float p = 0.f, q = 0.f;
                #pragma unroll
                for (int nb = 0; nb < 8; nb++) {
                    float v = fmaxf(acc2[ml][nb][i], 0.f);
                    acc2[ml][nb][i] = v;
                    p += v; q += v * v;
                }
                p += __shfl_xor(p, 1); q += __shfl_xor(q, 1);
                p += __shfl_xor(p, 2); q += __shfl_xor(q, 2);
                p += __shfl_xor(p, 4); q += __shfl_xor(q, 4);
                p += __shfl_xor(p, 8); q += __shfl_xor(q, 8);
                float mu = p * (1.f / 128.f);
                muv[i] = mu;
                rsv[i] = rsqrtf(q * (1.f / 128.f) - mu * mu + 1e-5f);
            }
            float av[8], apv[8];
            #pragma unroll
            for (int nb = 0; nb < 8; nb++) { av[nb] = 0.f; apv[nb] = 0.f; }
            int cur = rsorted[base + slot * 16 + g * 4];
            #pragma unroll
            for (int i = 0; i < 4; i++) {
                int erow = base + slot * 16 + g * 4 + i;
                int ri = (i == 0) ? cur : rsorted[erow];
                float vv[8], pp[8];
                #pragma unroll
                for (int nb = 0; nb < 8; nb++) {
                    float v = (acc2[ml][nb][i] - muv[i]) * rsv[i] * gamv[nb] + btv[nb];
                    vv[nb] = v;
                    pp[nb] = __shfl_xor(v, 1);
                }
                u32 olds[8];
                if (!(c15 & 1)) {
                    #pragma unroll
                    for (int nb = 0; nb < 8; nb++)
                        olds[nb] = *(const u32*)(el + (size_t)erow * L + nb * 16 + c15);
                }
                if (ri != cur) {
                    #pragma unroll
                    for (int nb = 0; nb < 8; nb++) {
                        if (!(c15 & 1)) {
                            u32 add = (u32)f2h(av[nb]) | ((u32)f2h(apv[nb]) << 16);
                            atomic_pk_add_f16(aggr + (size_t)cur * L + nb * 16 + c15, add);
                        }
                        av[nb] = 0.f; apv[nb] = 0.f;
                    }
                    cur = ri;
                }
                #pragma unroll
                for (int nb = 0; nb < 8; nb++) {
                    av[nb] += vv[nb];
                    apv[nb] += pp[nb];
                    if (!(c15 & 1)) {
                        float r0 = h2f((u16)(olds[nb] & 0xFFFFu)) + vv[nb];
                        float r1 = h2f((u16)(olds[nb] >> 16)) + pp[nb];
                        *(u32*)(el + (size_t)erow * L + nb * 16 + c15) =
                            (u32)f2h(r0) | ((u32)f2h(r1) << 16);
                    }
                }
            }
            #pragma unroll
            for (int nb = 0; nb < 8; nb++) {
                if (!(c15 & 1)) {
                    u32 add = (u32)f2h(av[nb]) | ((u32)f2h(apv[nb]) << 16);
                    atomic_pk_add_f16(aggr + (size_t)cur * L + nb * 16 + c15, add);
                }
            }
        }
    }
}

// ---------------------------------------------------------------------------
// fp16-MFMA GraphNetBlock node update — barrier-free 1-wave blocks (64 nodes).
// Also re-zeroes the aggr rows it consumed (fused zero for next step).
// ---------------------------------------------------------------------------
__global__ __launch_bounds__(64, 2) void node_block_kernel(
    u16* __restrict__ nl, u16* __restrict__ aggr,
    const u16* __restrict__ wp1, const float* __restrict__ b1,
    const u16* __restrict__ wp2, const float* __restrict__ b2,
    const float* __restrict__ gamma, const float* __restrict__ beta)
{
    __shared__ __align__(16) u16 hbuf[2][4][64][8];   // 8 KB, wave-private
    const int lane = threadIdx.x & 63;
    const int c15 = lane & 15, g = lane >> 4;
    const int base = blockIdx.x * 64;

    int rowL[4];
    #pragma unroll
    for (int m = 0; m < 4; m++) {
        int r = base + m * 16 + c15;
        rowL[m] = r < NNODES ? r : 0;
    }

    f32x4 acc[8][4];
    #pragma unroll
    for (int nb = 0; nb < 8; nb++) {
        float bv = b1[nb * 16 + c15];
        #pragma unroll
        for (int m = 0; m < 4; m++) acc[nb][m] = (f32x4){bv, bv, bv, bv};
    }
    f16x8 ab[2][4];
    f16x8 bbuf[2][8];
    #pragma unroll
    for (int nb = 0; nb < 8; nb++)
        bbuf[0][nb] = *(const f16x8*)(wp1 + ((size_t)(nb * 8) * 64 + lane) * 8);
    NODE_LOAD_A(0, 0);

    #pragma unroll
    for (int kk = 0; kk < 8; kk++) {
        if (kk < 7) {
            #pragma unroll
            for (int nb = 0; nb < 8; nb++)
                bbuf[(kk + 1) & 1][nb] =
                    *(const f16x8*)(wp1 + ((size_t)(nb * 8 + kk + 1) * 64 + lane) * 8);
            NODE_LOAD_A(kk + 1, (kk + 1) & 1);
        }
        __builtin_amdgcn_s_setprio(1);
        #pragma unroll
        for (int nb = 0; nb < 8; nb++) {
            #pragma unroll
            for (int m = 0; m < 4; m++)
                acc[nb][m] = __builtin_amdgcn_mfma_f32_16x16x32_f16(
                    ab[kk & 1][m], bbuf[kk & 1][nb], acc[nb][m], 0, 0, 0);
        }
        __builtin_amdgcn_s_setprio(0);
    }

    // fused aggr re-zero: each lane zeroes exactly the 16B chunks it consumed
    {
        const uint4 z4 = make_uint4(0u, 0u, 0u, 0u);
        #pragma unroll
        for (int m = 0; m < 4; m++) {
            int r = base + m * 16 + c15;
            if (r < NNODES) {
                #pragma unroll
                for (int kk = 0; kk < 4; kk++)
                    *(uint4*)(aggr + (size_t)r * L + kk * 32 + g * 8) = z4;
            }
        }
    }

    float gamv[8], btv[8];
    #pragma unroll
    for (int nb = 0; nb < 8; nb++) {
        gamv[nb] = gamma[nb * 16 + c15];
        btv[nb] = beta[nb * 16 + c15];
    }
    #pragma unroll
    for (int mp = 0; mp < 2; mp++) {
        #pragma unroll
        for (int ml = 0; ml < 2; ml++) {
            int m = mp * 2 + ml;
            #pragma unroll
            for (int nb = 0; nb < 8; nb++) {
                int kk2 = nb >> 1;
                int sub = ((nb & 1) << 1) | (c15 >> 3);
                int jj = c15 & 7;
                #pragma unroll
                for (int i = 0; i < 4; i++) {
                    float v = fmaxf(acc[nb][m][i], 0.f);
                    hbuf[ml][kk2][g * 4 + i + 16 * sub][jj] = f2h(v);
                }
            }
        }
        WAVE_LDS_FENCE();
        f32x4 acc2[2][8];
        #pragma unroll
        for (int nb = 0; nb < 8; nb++) {
            float bv = b2[nb * 16 + c15];
            acc2[0][nb] = (f32x4){bv, bv, bv, bv};
            acc2[1][nb] = (f32x4){bv, bv, bv, bv};
        }
        __builtin_amdgcn_s_setprio(1);
        #pragma unroll
        for (int kk = 0; kk < 4; kk++) {
            f16x8 a0 = *(const f16x8*)&hbuf[0][kk][lane][0];
            f16x8 a1 = *(const f16x8*)&hbuf[1][kk][lane][0];
            #pragma unroll
            for (int nb = 0; nb < 8; nb++) {
                f16x8 b = *(const f16x8*)(wp2 + ((size_t)(nb * 4 + kk) * 64 + lane) * 8);
                acc2[0][nb] = __builtin_amdgcn_mfma_f32_16x16x32_f16(a0, b, acc2[0][nb], 0, 0, 0);
                acc2[1][nb] = __builtin_amdgcn_mfma_f32_16x16x32_f16(a1, b, acc2[1][nb], 0, 0, 0);
            }
        }
        __builtin_amdgcn_s_setprio(0);
        WAVE_LDS_FENCE();
        #pragma unroll
        for (int ml = 0; ml < 2; ml++) {
            float muv[4], rsv[4];
            #pragma unroll
            for (int i = 0; i < 4; i++) {
                float p = 0.f, q = 0.f;
                #pragma unroll
                for (int nb = 0; nb < 8; nb++) {
                    float v = fmaxf(acc2[ml][nb][i], 0.f);
                    acc2[ml][nb][i] = v;
                    p += v; q += v * v;
                }
                p += __shfl_xor(p, 1); q += __shfl_xor(q, 1);
                p += __shfl_xor(p, 2); q += __shfl_xor(q, 2);
                p += __shfl_xor(p, 4); q += __shfl_xor(q, 4);
                p += __shfl_xor(p, 8); q += __shfl_xor(q, 8);
                float mu = p * (1.f / 128.f);
                muv[i] = mu;
                rsv[i] = rsqrtf(q * (1.f / 128.f) - mu * mu + 1e-5f);
            }
            #pragma unroll
            for (int i = 0; i < 4; i++) {
                int nrow = base + (mp * 2 + ml) * 16 + g * 4 + i;
                #pragma unroll
                for (int nb = 0; nb < 8; nb++) {
                    float v = (acc2[ml][nb][i] - muv[i]) * rsv[i] * gamv[nb] + btv[nb];
                    float pv = __shfl_xor(v, 1);
                    if (!(c15 & 1) && nrow < NNODES) {
                        int col = nb * 16 + c15;
                        u32* nlp = (u32*)(nl + (size_t)nrow * L + col);
                        u32 old = *nlp;
                        float r0 = h2f((u16)(old & 0xFFFFu)) + v;
                        float r1 = h2f((u16)(old >> 16)) + pv;
                        *nlp = (u32)f2h(r0) | ((u32)f2h(r1) << 16);
                    }
                }
            }
        }
    }
}

// ---------------------------------------------------------------------------
// Decoder: nl(fp16) -> 8 (swish) -> 15, scale by dt, write [TW,N,OUT] fp32
// ---------------------------------------------------------------------------
__global__ __launch_bounds__(256) void decode_kernel(
    const u16* __restrict__ nl,
    const float* __restrict__ w1, const float* __restrict__ b1,
    const float* __restrict__ w2, const float* __restrict__ b2,
    float* __restrict__ out)
{
    int n = blockIdx.x * blockDim.x + threadIdx.x;
    if (n >= NNODES) return;
    float h8[8];
    #pragma unroll
    for (int jj = 0; jj < 8; jj++) h8[jj] = b1[jj];
    const u16* row = nl + (size_t)n * L;
    for (int k = 0; k < L; k += 8) {
        float xv[8];
        load8h(row + k, xv);
        #pragma unroll
        for (int q = 0; q < 8; q++)
            #pragma unroll
            for (int jj = 0; jj < 8; jj++)
                h8[jj] += xv[q] * w1[(k + q) * 8 + jj];
    }
    #pragma unroll
    for (int jj = 0; jj < 8; jj++) { float v = h8[jj]; h8[jj] = v / (1.f + expf(-v)); }
    #pragma unroll
    for (int o15 = 0; o15 < 15; o15++) {
        float accv = b2[o15];
        #pragma unroll
        for (int jj = 0; jj < 8; jj++) accv += h8[jj] * w2[jj * 15 + o15];
        int tt = o15 / 3, oo = o15 - tt * 3;
        out[(size_t)tt * NNODES * 3 + (size_t)n * 3 + oo] = accv * (float)(tt + 1);
    }
}

// ---------------------------------------------------------------------------
extern "C" void kernel_launch(void* const* d_in, const int* in_sizes, int n_in,
                              void* d_out, int out_size, void* d_ws, size_t ws_size,
                              hipStream_t stream)
{
    // workspace layout (~267 MB)
    const size_t AG_B = (size_t)NNODES * L * 2;             //  25.6 MB
    const size_t EL_B = (size_t)NEDGES * L * 2;             // 204.8 MB
    const size_t NL_B = (size_t)NNODES * L * 2;             //  25.6 MB
    const size_t PE1_N = (size_t)15 * 8 * 12 * 64 * 8;      // u16 counts
    const size_t PE2_N = (size_t)15 * 8 * 4 * 64 * 8;
    const size_t PN1_N = (size_t)15 * 8 * 8 * 64 * 8;
    const size_t PN2_N = (size_t)15 * 8 * 4 * 64 * 8;
    const size_t PEE1_N = (size_t)8 * 64 * 8;               // ee layer1 (padded)
    const size_t PEE2_N = (size_t)8 * 4 * 64 * 8;           // ee layer2
    const size_t WPK_B = (PE1_N + PE2_N + PN1_N + PN2_N + PEE1_N + PEE2_N) * 2;
    const size_t SS_B  = (size_t)NEDGES * 4;                // ssorted
    const size_t RS_B  = (size_t)NEDGES * 4;                // rsorted
    const size_t CNT_B = (size_t)NNODES * 4;                // counts
    const size_t OFF_B = (size_t)NNODES * 4;                // offsets
    const size_t CUR_B = (size_t)NNODES * 4;                // cursor
    const size_t PAR_B = 2048;                              // partials (>=391*4)
    const size_t TOTAL = AG_B + EL_B + NL_B + WPK_B + SS_B + RS_B
                       + CNT_B + OFF_B + CUR_B + PAR_B;

    if (ws_size < TOTAL) {
        float val = 1000.0f + (float)((double)ws_size * 1e-6);
        diag_kernel<<<(out_size + 255) / 256, 256, 0, stream>>>((float*)d_out, out_size, val);
        return;
    }

    char* wsp = (char*)d_ws;
    u16* aggr = (u16*)wsp;                 wsp += AG_B;
    u16* el   = (u16*)wsp;                 wsp += EL_B;
    u16* nl   = (u16*)wsp;                 wsp += NL_B;
    u16* pe1  = (u16*)wsp;                 wsp += PE1_N * 2;
    u16* pe2  = (u16*)wsp;                 wsp += PE2_N * 2;
    u16* pn1  = (u16*)wsp;                 wsp += PN1_N * 2;
    u16* pn2  = (u16*)wsp;                 wsp += PN2_N * 2;
    u16* pee1 = (u16*)wsp;                 wsp += PEE1_N * 2;
    u16* pee2 = (u16*)wsp;                 wsp += PEE2_N * 2;
    int* ssorted = (int*)wsp;              wsp += SS_B;
    int* rsorted = (int*)wsp;              wsp += RS_B;
    u32* counts  = (u32*)wsp;              wsp += CNT_B;
    u32* offsets = (u32*)wsp;              wsp += OFF_B;
    u32* cursor  = (u32*)wsp;              wsp += CUR_B;
    u32* partials = (u32*)wsp;             wsp += PAR_B;
    float* out = (float*)d_out;

    const float* pvf       = (const float*)d_in[0];
    const float* matD      = (const float*)d_in[1];
    const float* matX      = (const float*)d_in[2];
    const int*   ntype     = (const int*)d_in[3];
    const float* mesh      = (const float*)d_in[4];
    const float* world     = (const float*)d_in[5];
    const int*   senders   = (const int*)d_in[6];
    const int*   receivers = (const int*)d_in[7];
    const float* nmean = (const float*)d_in[8];
    const float* nstd  = (const float*)d_in[9];
    const float* emean = (const float*)d_in[10];
    const float* estd  = (const float*)d_in[11];
    const float* ne_w1 = (const float*)d_in[12];
    const float* ne_b1 = (const float*)d_in[13];
    const float* ne_w2 = (const float*)d_in[14];
    const float* ne_b2 = (const float*)d_in[15];
    const float* ne_g  = (const float*)d_in[16];
    const float* ne_be = (const float*)d_in[17];
    const float* ee_w1 = (const float*)d_in[18];
    const float* ee_b1 = (const float*)d_in[19];
    const float* ee_w2 = (const float*)d_in[20];
    const float* ee_b2 = (const float*)d_in[21];
    const float* ee_g  = (const float*)d_in[22];
    const float* ee_be = (const float*)d_in[23];
    const float* blk_ew1 = (const float*)d_in[24];
    const float* blk_eb1 = (const float*)d_in[25];
    const float* blk_ew2 = (const float*)d_in[26];
    const float* blk_eb2 = (const float*)d_in[27];
    const float* blk_eg  = (const float*)d_in[28];
    const float* blk_ebt = (const float*)d_in[29];
    const float* blk_nw1 = (const float*)d_in[30];
    const float* blk_nb1 = (const float*)d_in[31];
    const float* blk_nw2 = (const float*)d_in[32];
    const float* blk_nb2 = (const float*)d_in[33];
    const float* blk_ng  = (const float*)d_in[34];
    const float* blk_nbt = (const float*)d_in[35];
    const float* dec_w1 = (const float*)d_in[36];
    const float* dec_b1 = (const float*)d_in[37];
    const float* dec_w2 = (const float*)d_in[38];
    const float* dec_b2 = (const float*)d_in[39];

    // --- counting sort of edges by receiver (one-time) ---
    zero_kernel<<<(int)((CNT_B / 16 + 255) / 256), 256, 0, stream>>>((uint4*)counts, (int)(CNT_B / 16));
    count_kernel<<<(NEDGES + 255) / 256, 256, 0, stream>>>(receivers, counts);
    scan_block_kernel<<<NBSCAN, 256, 0, stream>>>(counts, offsets, partials);
    scan_partials_kernel<<<1, 512, 0, stream>>>(partials);
    add_offsets_kernel<<<NBSCAN, 256, 0, stream>>>(offsets, partials, cursor);
    scatter_kernel<<<(NEDGES + 255) / 256, 256, 0, stream>>>(senders, receivers, cursor, ssorted, rsorted);

    // pack fp16 weights into B-fragment order
    pack_weights_kernel<<<(int)((15 * 8 * 12 * 64 + 255) / 256), 256, 0, stream>>>(
        blk_ew1, pe1, 384, 15);
    pack_weights_kernel<<<(int)((15 * 8 * 4 * 64 + 255) / 256), 256, 0, stream>>>(
        blk_ew2, pe2, 128, 15);
    pack_weights_kernel<<<(int)((15 * 8 * 8 * 64 + 255) / 256), 256, 0, stream>>>(
        blk_nw1, pn1, 256, 15);
    pack_weights_kernel<<<(int)((15 * 8 * 4 * 64 + 255) / 256), 256, 0, stream>>>(
        blk_nw2, pn2, 128, 15);
    pack_ee1_kernel<<<2, 256, 0, stream>>>(ee_w1, pee1);
    pack_weights_kernel<<<(int)((8 * 4 * 64 + 255) / 256), 256, 0, stream>>>(
        ee_w2, pee2, 128, 1);

    node_encode_kernel<<<(NNODES + 63) / 64, 256, 0, stream>>>(
        pvf, matD, matX, ntype, nmean, nstd,
        ne_w1, ne_b1, ne_w2, ne_b2, ne_g, ne_be, nl);
    edge_encode_kernel<<<NEDGES / 256, 256, 0, stream>>>(
        ssorted, rsorted, pvf, mesh, world, emean, estd,
        pee1, ee_b1, pee2, ee_b2, ee_g, ee_be, el);

    // one-time aggr zero; afterwards node_block re-zeroes for the next step
    const int nzero = NNODES * L * 2 / 16;
    zero_kernel<<<(nzero + 255) / 256, 256, 0, stream>>>((uint4*)aggr, nzero);

    for (int s = 0; s < 15; s++) {
        edge_block_kernel<<<NEDGES / 64, 64, 0, stream>>>(
            ssorted, rsorted, nl, el, aggr,
            pe1 + (size_t)s * 8 * 12 * 64 * 8, blk_eb1 + s * L,
            pe2 + (size_t)s * 8 * 4 * 64 * 8,  blk_eb2 + s * L,
            blk_eg + s * L, blk_ebt + s * L);
        node_block_kernel<<<(NNODES + 63) / 64, 64, 0, stream>>>(
            nl, aggr,
            pn1 + (size_t)s * 8 * 8 * 64 * 8, blk_nb1 + s * L,
            pn2 + (size_t)s * 8 * 4 * 64 * 8, blk_nb2 + s * L,
            blk_ng + s * L, blk_nbt + s * L);
    }

    decode_kernel<<<(NNODES + 255) / 256, 256, 0, stream>>>(
        nl, dec_w1, dec_b1, dec_w2, dec_b2, out);
}

// Round 17
// 6847.187 us; speedup vs baseline: 1.1842x; 1.1842x over previous
//
#include <hip/hip_runtime.h>
#include <math.h>

#define NNODES 100000
#define NEDGES 800000
#define L 128
#define NBSCAN ((NNODES + 255) / 256)   // 391 scan blocks

typedef unsigned short u16;
typedef unsigned int u32;
typedef unsigned short ushort8 __attribute__((ext_vector_type(8)));
typedef _Float16 f16x8 __attribute__((ext_vector_type(8)));
typedef __attribute__((ext_vector_type(4))) float f32x4;

// ---- conversions -----------------------------------------------------------
static __device__ __forceinline__ float h2f(u16 u) {       // fp16 -> f32
    _Float16 h;
    __builtin_memcpy(&h, &u, 2);
    return (float)h;
}
static __device__ __forceinline__ u16 f2h(float x) {       // f32 -> fp16 RNE
    _Float16 h = (_Float16)x;
    u16 u;
    __builtin_memcpy(&u, &h, 2);
    return u;
}
static __device__ __forceinline__ void load8h(const u16* p, float* d) {
    ushort8 v = *(const ushort8*)p;
    #pragma unroll
    for (int k = 0; k < 8; k++) d[k] = h2f(v[k]);
}
// HW packed fp16x2 atomic add (gfx90a+), no memory clobber (nothing here
// reads aggr; clobber would serialize the epilogue).
static __device__ __forceinline__ void atomic_pk_add_f16(u16* addr, u32 data) {
    asm volatile("global_atomic_pk_add_f16 %0, %1, off" :: "v"(addr), "v"(data));
}

// ---------------------------------------------------------------------------
__global__ __launch_bounds__(256) void zero_kernel(uint4* p, int n) {
    int i = blockIdx.x * 256 + threadIdx.x;
    if (i < n) p[i] = make_uint4(0u, 0u, 0u, 0u);
}

__global__ __launch_bounds__(256) void diag_kernel(float* out, int n, float val) {
    int i = blockIdx.x * 256 + threadIdx.x;
    if (i < n) out[i] = val;
}

// ---------------------------------------------------------------------------
// Counting sort of edges by receiver: counts -> scan -> scatter.
// ---------------------------------------------------------------------------
__global__ __launch_bounds__(256) void count_kernel(
    const int* __restrict__ receivers, u32* __restrict__ counts)
{
    int e = blockIdx.x * 256 + threadIdx.x;
    if (e < NEDGES) atomicAdd(&counts[receivers[e]], 1u);
}

__global__ __launch_bounds__(256) void scan_block_kernel(
    const u32* __restrict__ counts, u32* __restrict__ offsets,
    u32* __restrict__ partials)
{
    __shared__ u32 sh[256];
    int i = blockIdx.x * 256 + threadIdx.x;
    u32 c = (i < NNODES) ? counts[i] : 0u;
    sh[threadIdx.x] = c;
    __syncthreads();
    #pragma unroll
    for (int d = 1; d < 256; d <<= 1) {
        u32 v = (threadIdx.x >= d) ? sh[threadIdx.x - d] : 0u;
        __syncthreads();
        sh[threadIdx.x] += v;
        __syncthreads();
    }
    if (i < NNODES) offsets[i] = sh[threadIdx.x] - c;   // excl within block
    if (threadIdx.x == 255) partials[blockIdx.x] = sh[255];
}

__global__ __launch_bounds__(512) void scan_partials_kernel(u32* __restrict__ partials)
{
    __shared__ u32 sh[512];
    int x = threadIdx.x;
    u32 c = (x < NBSCAN) ? partials[x] : 0u;
    sh[x] = c;
    __syncthreads();
    #pragma unroll
    for (int d = 1; d < 512; d <<= 1) {
        u32 v = (x >= d) ? sh[x - d] : 0u;
        __syncthreads();
        sh[x] += v;
        __syncthreads();
    }
    if (x < NBSCAN) partials[x] = sh[x] - c;            // exclusive
}

__global__ __launch_bounds__(256) void add_offsets_kernel(
    u32* __restrict__ offsets, const u32* __restrict__ partials,
    u32* __restrict__ cursor)
{
    int i = blockIdx.x * 256 + threadIdx.x;
    if (i < NNODES) {
        u32 v = offsets[i] + partials[blockIdx.x];
        offsets[i] = v;
        cursor[i] = v;
    }
}

__global__ __launch_bounds__(256) void scatter_kernel(
    const int* __restrict__ senders, const int* __restrict__ receivers,
    u32* __restrict__ cursor, int* __restrict__ ssorted, int* __restrict__ rsorted)
{
    int e = blockIdx.x * 256 + threadIdx.x;
    if (e < NEDGES) {
        int r = receivers[e];
        u32 pos = atomicAdd(&cursor[r], 1u);
        ssorted[pos] = senders[e];
        rsorted[pos] = r;
    }
}

// ---------------------------------------------------------------------------
// Weight pre-pack into MFMA B-fragment order, single fp16.
// ---------------------------------------------------------------------------
__global__ __launch_bounds__(256) void pack_weights_kernel(
    const float* __restrict__ src, u16* __restrict__ dst, int K, int nsteps)
{
    int idx = blockIdx.x * 256 + threadIdx.x;
    int nkk = K >> 5;
    int total = nsteps * 8 * nkk * 64;
    if (idx >= total) return;
    int lane = idx & 63;
    int rest = idx >> 6;
    int kk = rest % nkk; rest /= nkk;
    int nb = rest & 7;
    int s = rest >> 3;
    int c15 = lane & 15, gg = lane >> 4;
    const float* w = src + (size_t)s * K * 128;
    u16 out[8];
    #pragma unroll
    for (int j = 0; j < 8; j++) {
        int k = kk * 32 + gg * 8 + j;
        out[j] = f2h(w[(size_t)k * 128 + nb * 16 + c15]);
    }
    *(ushort8*)(dst + (size_t)idx * 8) = *(ushort8*)out;
}

// pack edge-encoder layer1 (7x128), K padded to 32 with zero rows
__global__ __launch_bounds__(256) void pack_ee1_kernel(
    const float* __restrict__ src, u16* __restrict__ dst)
{
    int idx = blockIdx.x * 256 + threadIdx.x;
    if (idx >= 8 * 64) return;
    int lane = idx & 63, nb = idx >> 6;
    int c15 = lane & 15, gg = lane >> 4;
    u16 out[8];
    #pragma unroll
    for (int j = 0; j < 8; j++) {
        int k = gg * 8 + j;
        out[j] = (k < 7) ? f2h(src[(size_t)k * 128 + nb * 16 + c15]) : (u16)0;
    }
    *(ushort8*)(dst + (size_t)idx * 8) = *(ushort8*)out;
}

// ---------------------------------------------------------------------------
// Node encoder: feats(6) -> 128 -> 128 -> LN -> fp16 nl  (64 nodes / block)
// ---------------------------------------------------------------------------
__global__ __launch_bounds__(256) void node_encode_kernel(
    const float* __restrict__ pvf, const float* __restrict__ matD,
    const float* __restrict__ matX, const int* __restrict__ ntype,
    const float* __restrict__ nmean, const float* __restrict__ nstd,
    const float* __restrict__ w1, const float* __restrict__ b1,
    const float* __restrict__ w2, const float* __restrict__ b2,
    const float* __restrict__ g, const float* __restrict__ be,
    u16* __restrict__ nl)
{
    __shared__ float xs[64][8];
    __shared__ float h[64][132];
    const int t = threadIdx.x;
    const int base = blockIdx.x * 64;
    if (t < 64) {
        int n = base + t;
        if (n < NNODES) {
            int nt = ntype[n];
            float f[6];
            f[0] = pvf[n]; f[1] = matD[n]; f[2] = matX[n];
            f[3] = (nt == 0) ? 1.f : 0.f;
            f[4] = (nt == 1) ? 1.f : 0.f;
            f[5] = (nt == 2) ? 1.f : 0.f;
            #pragma unroll
            for (int k = 0; k < 6; k++) xs[t][k] = (f[k] - nmean[k]) / nstd[k];
        } else {
            #pragma unroll
            for (int k = 0; k < 6; k++) xs[t][k] = 0.f;
        }
    }
    __syncthreads();
    const int j = t & 127, half = t >> 7;
    for (int i = 0; i < 32; i++) {
        int e = half * 32 + i;
        float acc = b1[j];
        #pragma unroll
        for (int k = 0; k < 6; k++) acc += xs[e][k] * w1[k * L + j];
        h[e][j] = fmaxf(acc, 0.f);
    }
    __syncthreads();
    float acc2[32];
    #pragma unroll
    for (int i = 0; i < 32; i++) acc2[i] = b2[j];
    for (int k4 = 0; k4 < 32; k4++) {
        const float* wp = w2 + k4 * 4 * L + j;
        float wa = wp[0], wb = wp[L], wc = wp[2 * L], wd = wp[3 * L];
        #pragma unroll
        for (int i = 0; i < 32; i++) {
            const float4 xv = *(const float4*)&h[half * 32 + i][k4 * 4];
            acc2[i] += xv.x * wa + xv.y * wb + xv.z * wc + xv.w * wd;
        }
    }
    __syncthreads();
    #pragma unroll
    for (int i = 0; i < 32; i++) h[half * 32 + i][j] = fmaxf(acc2[i], 0.f);
    __syncthreads();
    {
        const int e = t >> 2, tg = t & 3;
        float sum = 0.f, sq = 0.f;
        #pragma unroll
        for (int jj = 0; jj < 32; jj++) { float v = h[e][tg * 32 + jj]; sum += v; sq += v * v; }
        sum += __shfl_xor(sum, 1); sq += __shfl_xor(sq, 1);
        sum += __shfl_xor(sum, 2); sq += __shfl_xor(sq, 2);
        float mu = sum * (1.f / 128.f);
        float rstd = rsqrtf(sq * (1.f / 128.f) - mu * mu + 1e-5f);
        int n = base + e;
        if (n < NNODES) {
            u32* nrow = (u32*)(nl + (size_t)n * L) + tg * 16;
            #pragma unroll
            for (int p = 0; p < 16; p++) {
                int f0 = tg * 32 + 2 * p;
                float v0 = (h[e][f0] - mu) * rstd * g[f0] + be[f0];
                float v1 = (h[e][f0 + 1] - mu) * rstd * g[f0 + 1] + be[f0 + 1];
                nrow[p] = (u32)f2h(v0) | ((u32)f2h(v1) << 16);
            }
        }
    }
}

// ---------------------------------------------------------------------------
// MFMA edge encoder (sorted edge space): feats(7, padded to K=32) -> 128
// -> 128 -> LN -> fp16 el.  256 edges/block, 4 waves, wave = 64 rows.
// Same fragment/epilogue structure as edge_block (no residual, no atomics).
// ---------------------------------------------------------------------------
__global__ __launch_bounds__(256, 2) void edge_encode_kernel(
    const int* __restrict__ ssorted, const int* __restrict__ rsorted,
    const float* __restrict__ pvf, const float* __restrict__ mesh,
    const float* __restrict__ world,
    const float* __restrict__ emean, const float* __restrict__ estd,
    const u16* __restrict__ wp1, const float* __restrict__ b1,
    const u16* __restrict__ wp2, const float* __restrict__ b2,
    const float* __restrict__ gamma, const float* __restrict__ beta,
    u16* __restrict__ el)
{
    __shared__ __align__(16) u16 hbuf[4][2][4][64][8];   // 32 KB
    const int t = threadIdx.x;
    const int wid = t >> 6, lane = t & 63;
    const int c15 = lane & 15, g = lane >> 4;
    const int base = blockIdx.x * 256 + wid * 64;   // E % 256 == 0

    // A-fragments: only the g==0 k-chunk carries the 7 features (rest zero)
    f16x8 a[4];
    #pragma unroll
    for (int m = 0; m < 4; m++) {
        f16x8 v;
        #pragma unroll
        for (int k = 0; k < 8; k++) v[k] = (_Float16)0.f;
        if (g == 0) {
            int e = base + m * 16 + c15;
            int s = ssorted[e], r = rsorted[e];
            float rmx = mesh[s * 2] - mesh[r * 2];
            float rmy = mesh[s * 2 + 1] - mesh[r * 2 + 1];
            float dm = sqrtf(rmx * rmx + rmy * rmy);
            float rwx = world[s * 2] - world[r * 2];
            float rwy = world[s * 2 + 1] - world[r * 2 + 1];
            float dw = sqrtf(rwx * rwx + rwy * rwy);
            float pg = pvf[s] - pvf[r];
            float f[7] = {rmx, rmy, dm, rwx, rwy, dw, pg};
            #pragma unroll
            for (int k = 0; k < 7; k++)
                v[k] = (_Float16)((f[k] - emean[k]) / estd[k]);
        }
        a[m] = v;
    }

    // ---- layer 1: single k-step (K=32 padded) ----
    f32x4 acc[8][4];
    #pragma unroll
    for (int nb = 0; nb < 8; nb++) {
        float bv = b1[nb * 16 + c15];
        #pragma unroll
        for (int m = 0; m < 4; m++) acc[nb][m] = (f32x4){bv, bv, bv, bv};
    }
    #pragma unroll
    for (int nb = 0; nb < 8; nb++) {
        f16x8 b = *(const f16x8*)(wp1 + ((size_t)(nb * 64 + lane)) * 8);
        #pragma unroll
        for (int m = 0; m < 4; m++)
            acc[nb][m] = __builtin_amdgcn_mfma_f32_16x16x32_f16(a[m], b, acc[nb][m], 0, 0, 0);
    }

    // ---- layer 2 in m-pairs ----
    float gamv[8], btv[8];
    #pragma unroll
    for (int nb = 0; nb < 8; nb++) {
        gamv[nb] = gamma[nb * 16 + c15];
        btv[nb] = beta[nb * 16 + c15];
    }
    #pragma unroll
    for (int mp = 0; mp < 2; mp++) {
        #pragma unroll
        for (int ml = 0; ml < 2; ml++) {
            int m = mp * 2 + ml;
            #pragma unroll
            for (int nb = 0; nb < 8; nb++) {
                int kk2 = nb >> 1;
                int sub = ((nb & 1) << 1) | (c15 >> 3);
                int jj = c15 & 7;
                #pragma unroll
                for (int i = 0; i < 4; i++) {
                    float v = fmaxf(acc[nb][m][i], 0.f);
                    hbuf[wid][ml][kk2][g * 4 + i + 16 * sub][jj] = f2h(v);
                }
            }
        }
        f32x4 acc2[2][8];
        #pragma unroll
        for (int nb = 0; nb < 8; nb++) {
            float bv = b2[nb * 16 + c15];
            acc2[0][nb] = (f32x4){bv, bv, bv, bv};
            acc2[1][nb] = (f32x4){bv, bv, bv, bv};
        }
        #pragma unroll
        for (int kk = 0; kk < 4; kk++) {
            f16x8 a0 = *(const f16x8*)&hbuf[wid][0][kk][lane][0];
            f16x8 a1 = *(const f16x8*)&hbuf[wid][1][kk][lane][0];
            #pragma unroll
            for (int nb = 0; nb < 8; nb++) {
                f16x8 b = *(const f16x8*)(wp2 + ((size_t)(nb * 4 + kk) * 64 + lane) * 8);
                acc2[0][nb] = __builtin_amdgcn_mfma_f32_16x16x32_f16(a0, b, acc2[0][nb], 0, 0, 0);
                acc2[1][nb] = __builtin_amdgcn_mfma_f32_16x16x32_f16(a1, b, acc2[1][nb], 0, 0, 0);
            }
        }
        #pragma unroll
        for (int ml = 0; ml < 2; ml++) {
            float muv[4], rsv[4];
            #pragma unroll
            for (int i = 0; i < 4; i++) {
                float p = 0.f, q = 0.f;
                #pragma unroll
                for (int nb = 0; nb < 8; nb++) {
                    float v = fmaxf(acc2[ml][nb][i], 0.f);
                    acc2[ml][nb][i] = v;
                    p += v; q += v * v;
                }
                p += __shfl_xor(p, 1); q += __shfl_xor(q, 1);
                p += __shfl_xor(p, 2); q += __shfl_xor(q, 2);
                p += __shfl_xor(p, 4); q += __shfl_xor(q, 4);
                p += __shfl_xor(p, 8); q += __shfl_xor(q, 8);
                float mu = p * (1.f / 128.f);
                muv[i] = mu;
                rsv[i] = rsqrtf(q * (1.f / 128.f) - mu * mu + 1e-5f);
            }
            #pragma unroll
            for (int i = 0; i < 4; i++) {
                int erow = base + (mp * 2 + ml) * 16 + g * 4 + i;
                #pragma unroll
                for (int nb = 0; nb < 8; nb++) {
                    float v = (acc2[ml][nb][i] - muv[i]) * rsv[i] * gamv[nb] + btv[nb];
                    float pv = __shfl_xor(v, 1);
                    if (!(c15 & 1)) {
                        *(u32*)(el + (size_t)erow * L + nb * 16 + c15) =
                            (u32)f2h(v) | ((u32)f2h(pv) << 16);
                    }
                }
            }
        }
    }
}

// A-gather for edge layer-1, k-step nk (0..11), into ab[slot]
#define EDGE_LOAD_A(nk, slot)                                                     \
    {                                                                             \
        _Pragma("unroll")                                                         \
        for (int m = 0; m < 4; m++) {                                             \
            const u16* ap;                                                        \
            if ((nk) < 4)      ap = nl + (size_t)sA[m] * L + (nk) * 32 + g * 8;   \
            else if ((nk) < 8) ap = nl + (size_t)rA[m] * L + ((nk) - 4) * 32 + g * 8; \
            else               ap = el + (size_t)(base + m * 16 + c15) * L + ((nk) - 8) * 32 + g * 8; \
            ab[slot][m] = *(const f16x8*)ap;                                      \
        }                                                                         \
    }

#define NODE_LOAD_A(nk, slot)                                                     \
    {                                                                             \
        _Pragma("unroll")                                                         \
        for (int m = 0; m < 4; m++) {                                             \
            const u16* ap = ((nk) < 4) ? (nl + (size_t)rowL[m] * L + (nk) * 32 + g * 8) \
                                       : (aggr + (size_t)rowL[m] * L + ((nk) - 4) * 32 + g * 8); \
            ab[slot][m] = *(const f16x8*)ap;                                      \
        }                                                                         \
    }

// lgkm-only barrier: LDS ops drained, global loads stay in flight
#define LGKM_BARRIER()                                          \
    asm volatile("s_waitcnt lgkmcnt(0)" ::: "memory");          \
    __builtin_amdgcn_sched_barrier(0);                          \
    __builtin_amdgcn_s_barrier();

// ---------------------------------------------------------------------------
// fp16-MFMA GraphNetBlock edge update (sorted edge space). T14 reg-staged
// weight pipeline + run-merged aggr atomics + T5 setprio + batched epilogue.
// ---------------------------------------------------------------------------
__global__ __launch_bounds__(256, 2) void edge_block_kernel(
    const int* __restrict__ ssorted, const int* __restrict__ rsorted,
    const u16* __restrict__ nl, u16* __restrict__ el, u16* __restrict__ aggr,
    const u16* __restrict__ wp1, const float* __restrict__ b1,
    const u16* __restrict__ wp2, const float* __restrict__ b2,
    const float* __restrict__ gamma, const float* __restrict__ beta)
{
    __shared__ __align__(16) u16 wbuf[2][8][64][8];      // 16 KB B dbuf
    __shared__ __align__(16) u16 hbuf[4][2][4][64][8];   // 32 KB h-frag
    const int t = threadIdx.x;
    const int wid = t >> 6, lane = t & 63;
    const int c15 = lane & 15, g = lane >> 4;
    const int base = blockIdx.x * 256 + wid * 64;   // E % 256 == 0

    int sA[4], rA[4];
    #pragma unroll
    for (int m = 0; m < 4; m++) {
        sA[m] = ssorted[base + m * 16 + c15];
        rA[m] = rsorted[base + m * 16 + c15];
    }

    // ---- layer 1: K = 384 (12 k-steps), M = 64, T14 pipeline ----
    f32x4 acc[8][4];
    #pragma unroll
    for (int nb = 0; nb < 8; nb++) {
        float bv = b1[nb * 16 + c15];
        #pragma unroll
        for (int m = 0; m < 4; m++) acc[nb][m] = (f32x4){bv, bv, bv, bv};
    }
    f16x8 ab[2][4];
    f16x8 w0, w1;
    w0 = *(const f16x8*)(wp1 + ((size_t)((2 * wid) * 12 + 0) * 64 + lane) * 8);
    w1 = *(const f16x8*)(wp1 + ((size_t)((2 * wid + 1) * 12 + 0) * 64 + lane) * 8);
    EDGE_LOAD_A(0, 0);
    *(f16x8*)&wbuf[0][2 * wid][lane][0] = w0;
    *(f16x8*)&wbuf[0][2 * wid + 1][lane][0] = w1;
    LGKM_BARRIER();

    #pragma unroll
    for (int kk = 0; kk < 12; kk++) {
        if (kk < 11) {
            w0 = *(const f16x8*)(wp1 + ((size_t)((2 * wid) * 12 + kk + 1) * 64 + lane) * 8);
            w1 = *(const f16x8*)(wp1 + ((size_t)((2 * wid + 1) * 12 + kk + 1) * 64 + lane) * 8);
            EDGE_LOAD_A(kk + 1, (kk + 1) & 1);
        }
        __builtin_amdgcn_s_setprio(1);
        #pragma unroll
        for (int nb = 0; nb < 8; nb++) {
            f16x8 b = *(const f16x8*)&wbuf[kk & 1][nb][lane][0];
            #pragma unroll
            for (int m = 0; m < 4; m++)
                acc[nb][m] = __builtin_amdgcn_mfma_f32_16x16x32_f16(ab[kk & 1][m], b, acc[nb][m], 0, 0, 0);
        }
        __builtin_amdgcn_s_setprio(0);
        if (kk < 11) {
            *(f16x8*)&wbuf[(kk + 1) & 1][2 * wid][lane][0] = w0;
            *(f16x8*)&wbuf[(kk + 1) & 1][2 * wid + 1][lane][0] = w1;
            LGKM_BARRIER();
        }
    }

    // ---- layer 2 in m-pairs (B from global/L2) ----
    float gamv[8], btv[8];
    #pragma unroll
    for (int nb = 0; nb < 8; nb++) {
        gamv[nb] = gamma[nb * 16 + c15];
        btv[nb] = beta[nb * 16 + c15];
    }
    #pragma unroll
    for (int mp = 0; mp < 2; mp++) {
        #pragma unroll
        for (int ml = 0; ml < 2; ml++) {
            int m = mp * 2 + ml;
            #pragma unroll
            for (int nb = 0; nb < 8; nb++) {
                int kk2 = nb >> 1;
                int sub = ((nb & 1) << 1) | (c15 >> 3);
                int jj = c15 & 7;
                #pragma unroll
                for (int i = 0; i < 4; i++) {
                    float v = fmaxf(acc[nb][m][i], 0.f);
                    hbuf[wid][ml][kk2][g * 4 + i + 16 * sub][jj] = f2h(v);
                }
            }
        }
        f32x4 acc2[2][8];
        #pragma unroll
        for (int nb = 0; nb < 8; nb++) {
            float bv = b2[nb * 16 + c15];
            acc2[0][nb] = (f32x4){bv, bv, bv, bv};
            acc2[1][nb] = (f32x4){bv, bv, bv, bv};
        }
        __builtin_amdgcn_s_setprio(1);
        #pragma unroll
        for (int kk = 0; kk < 4; kk++) {
            f16x8 a0 = *(const f16x8*)&hbuf[wid][0][kk][lane][0];
            f16x8 a1 = *(const f16x8*)&hbuf[wid][1][kk][lane][0];
            #pragma unroll
            for (int nb = 0; nb < 8; nb++) {
                f16x8 b = *(const f16x8*)(wp2 + ((size_t)(nb * 4 + kk) * 64 + lane) * 8);
                acc2[0][nb] = __builtin_amdgcn_mfma_f32_16x16x32_f16(a0, b, acc2[0][nb], 0, 0, 0);
                acc2[1][nb] = __builtin_amdgcn_mfma_f32_16x16x32_f16(a1, b, acc2[1][nb], 0, 0, 0);
            }
        }
        __builtin_amdgcn_s_setprio(0);
        // ---- relu + LN + residual + run-merged aggr atomics, per m ----
        #pragma unroll
        for (int ml = 0; ml < 2; ml++) {
            const int slot = mp * 2 + ml;
            float muv[4], rsv[4];
            #pragma unroll
            for (int i = 0; i < 4; i++) {
                float p = 0.f, q = 0.f;
                #pragma unroll
                for (int nb = 0; nb < 8; nb++) {
                    float v = fmaxf(acc2[ml][nb][i], 0.f);
                    acc2[ml][nb][i] = v;
                    p += v; q += v * v;
                }
                p += __shfl_xor(p, 1); q += __shfl_xor(q, 1);
                p += __shfl_xor(p, 2); q += __shfl_xor(q, 2);
                p += __shfl_xor(p, 4); q += __shfl_xor(q, 4);
                p += __shfl_xor(p, 8); q += __shfl_xor(q, 8);
                float mu = p * (1.f / 128.f);
                muv[i] = mu;
                rsv[i] = rsqrtf(q * (1.f / 128.f) - mu * mu + 1e-5f);
            }
            float av[8], apv[8];
            #pragma unroll
            for (int nb = 0; nb < 8; nb++) { av[nb] = 0.f; apv[nb] = 0.f; }
            int cur = rsorted[base + slot * 16 + g * 4];
            #pragma unroll
            for (int i = 0; i < 4; i++) {
                int erow = base + slot * 16 + g * 4 + i;
                int ri = (i == 0) ? cur : rsorted[erow];
                float vv[8], pp[8];
                #pragma unroll
                for (int nb = 0; nb < 8; nb++) {
                    float v = (acc2[ml][nb][i] - muv[i]) * rsv[i] * gamv[nb] + btv[nb];
                    vv[nb] = v;
                    pp[nb] = __shfl_xor(v, 1);
                }
                u32 olds[8];
                if (!(c15 & 1)) {
                    #pragma unroll
                    for (int nb = 0; nb < 8; nb++)
                        olds[nb] = *(const u32*)(el + (size_t)erow * L + nb * 16 + c15);
                }
                if (ri != cur) {
                    #pragma unroll
                    for (int nb = 0; nb < 8; nb++) {
                        if (!(c15 & 1)) {
                            u32 add = (u32)f2h(av[nb]) | ((u32)f2h(apv[nb]) << 16);
                            atomic_pk_add_f16(aggr + (size_t)cur * L + nb * 16 + c15, add);
                        }
                        av[nb] = 0.f; apv[nb] = 0.f;
                    }
                    cur = ri;
                }
                #pragma unroll
                for (int nb = 0; nb < 8; nb++) {
                    av[nb] += vv[nb];
                    apv[nb] += pp[nb];
                    if (!(c15 & 1)) {
                        float r0 = h2f((u16)(olds[nb] & 0xFFFFu)) + vv[nb];
                        float r1 = h2f((u16)(olds[nb] >> 16)) + pp[nb];
                        *(u32*)(el + (size_t)erow * L + nb * 16 + c15) =
                            (u32)f2h(r0) | ((u32)f2h(r1) << 16);
                    }
                }
            }
            #pragma unroll
            for (int nb = 0; nb < 8; nb++) {
                if (!(c15 & 1)) {
                    u32 add = (u32)f2h(av[nb]) | ((u32)f2h(apv[nb]) << 16);
                    atomic_pk_add_f16(aggr + (size_t)cur * L + nb * 16 + c15, add);
                }
            }
        }
    }
}

// ---------------------------------------------------------------------------
// fp16-MFMA GraphNetBlock node update, T14 pipeline like edge_block.
// Also re-zeroes the aggr rows it consumed (fused zero for next step).
// ---------------------------------------------------------------------------
__global__ __launch_bounds__(256, 2) void node_block_kernel(
    u16* __restrict__ nl, u16* __restrict__ aggr,
    const u16* __restrict__ wp1, const float* __restrict__ b1,
    const u16* __restrict__ wp2, const float* __restrict__ b2,
    const float* __restrict__ gamma, const float* __restrict__ beta)
{
    __shared__ __align__(16) u16 wbuf[2][8][64][8];      // 16 KB
    __shared__ __align__(16) u16 hbuf[4][2][4][64][8];   // 32 KB
    const int t = threadIdx.x;
    const int wid = t >> 6, lane = t & 63;
    const int c15 = lane & 15, g = lane >> 4;
    const int base = blockIdx.x * 256 + wid * 64;

    int rowL[4];
    #pragma unroll
    for (int m = 0; m < 4; m++) {
        int r = base + m * 16 + c15;
        rowL[m] = r < NNODES ? r : 0;
    }

    f32x4 acc[8][4];
    #pragma unroll
    for (int nb = 0; nb < 8; nb++) {
        float bv = b1[nb * 16 + c15];
        #pragma unroll
        for (int m = 0; m < 4; m++) acc[nb][m] = (f32x4){bv, bv, bv, bv};
    }
    f16x8 ab[2][4];
    f16x8 w0, w1;
    w0 = *(const f16x8*)(wp1 + ((size_t)((2 * wid) * 8 + 0) * 64 + lane) * 8);
    w1 = *(const f16x8*)(wp1 + ((size_t)((2 * wid + 1) * 8 + 0) * 64 + lane) * 8);
    NODE_LOAD_A(0, 0);
    *(f16x8*)&wbuf[0][2 * wid][lane][0] = w0;
    *(f16x8*)&wbuf[0][2 * wid + 1][lane][0] = w1;
    LGKM_BARRIER();

    #pragma unroll
    for (int kk = 0; kk < 8; kk++) {
        if (kk < 7) {
            w0 = *(const f16x8*)(wp1 + ((size_t)((2 * wid) * 8 + kk + 1) * 64 + lane) * 8);
            w1 = *(const f16x8*)(wp1 + ((size_t)((2 * wid + 1) * 8 + kk + 1) * 64 + lane) * 8);
            NODE_LOAD_A(kk + 1, (kk + 1) & 1);
        }
        __builtin_amdgcn_s_setprio(1);
        #pragma unroll
        for (int nb = 0; nb < 8; nb++) {
            f16x8 b = *(const f16x8*)&wbuf[kk & 1][nb][lane][0];
            #pragma unroll
            for (int m = 0; m < 4; m++)
                acc[nb][m] = __builtin_amdgcn_mfma_f32_16x16x32_f16(ab[kk & 1][m], b, acc[nb][m], 0, 0, 0);
        }
        __builtin_amdgcn_s_setprio(0);
        if (kk < 7) {
            *(f16x8*)&wbuf[(kk + 1) & 1][2 * wid][lane][0] = w0;
            *(f16x8*)&wbuf[(kk + 1) & 1][2 * wid + 1][lane][0] = w1;
            LGKM_BARRIER();
        }
    }

    // fused aggr re-zero
    {
        const uint4 z4 = make_uint4(0u, 0u, 0u, 0u);
        #pragma unroll
        for (int m = 0; m < 4; m++) {
            int r = base + m * 16 + c15;
            if (r < NNODES) {
                #pragma unroll
                for (int kk = 0; kk < 4; kk++)
                    *(uint4*)(aggr + (size_t)r * L + kk * 32 + g * 8) = z4;
            }
        }
    }

    float gamv[8], btv[8];
    #pragma unroll
    for (int nb = 0; nb < 8; nb++) {
        gamv[nb] = gamma[nb * 16 + c15];
        btv[nb] = beta[nb * 16 + c15];
    }
    #pragma unroll
    for (int mp = 0; mp < 2; mp++) {
        #pragma unroll
        for (int ml = 0; ml < 2; ml++) {
            int m = mp * 2 + ml;
            #pragma unroll
            for (int nb = 0; nb < 8; nb++) {
                int kk2 = nb >> 1;
                int sub = ((nb & 1) << 1) | (c15 >> 3);
                int jj = c15 & 7;
                #pragma unroll
                for (int i = 0; i < 4; i++) {
                    float v = fmaxf(acc[nb][m][i], 0.f);
                    hbuf[wid][ml][kk2][g * 4 + i + 16 * sub][jj] = f2h(v);
                }
            }
        }
        f32x4 acc2[2][8];
        #pragma unroll
        for (int nb = 0; nb < 8; nb++) {
            float bv = b2[nb * 16 + c15];
            acc2[0][nb] = (f32x4){bv, bv, bv, bv};
            acc2[1][nb] = (f32x4){bv, bv, bv, bv};
        }
        __builtin_amdgcn_s_setprio(1);
        #pragma unroll
        for (int kk = 0; kk < 4; kk++) {
            f16x8 a0 = *(const f16x8*)&hbuf[wid][0][kk][lane][0];
            f16x8 a1 = *(const f16x8*)&hbuf[wid][1][kk][lane][0];
            #pragma unroll
            for (int nb = 0; nb < 8; nb++) {
                f16x8 b = *(const f16x8*)(wp2 + ((size_t)(nb * 4 + kk) * 64 + lane) * 8);
                acc2[0][nb] = __builtin_amdgcn_mfma_f32_16x16x32_f16(a0, b, acc2[0][nb], 0, 0, 0);
                acc2[1][nb] = __builtin_amdgcn_mfma_f32_16x16x32_f16(a1, b, acc2[1][nb], 0, 0, 0);
            }
        }
        __builtin_amdgcn_s_setprio(0);
        #pragma unroll
        for (int ml = 0; ml < 2; ml++) {
            float muv[4], rsv[4];
            #pragma unroll
            for (int i = 0; i < 4; i++) {
                float p = 0.f, q = 0.f;
                #pragma unroll
                for (int nb = 0; nb < 8; nb++) {
                    float v = fmaxf(acc2[ml][nb][i], 0.f);
                    acc2[ml][nb][i] = v;
                    p += v; q += v * v;
                }
                p += __shfl_xor(p, 1); q += __shfl_xor(q, 1);
                p += __shfl_xor(p, 2); q += __shfl_xor(q, 2);
                p += __shfl_xor(p, 4); q += __shfl_xor(q, 4);
                p += __shfl_xor(p, 8); q += __shfl_xor(q, 8);
                float mu = p * (1.f / 128.f);
                muv[i] = mu;
                rsv[i] = rsqrtf(q * (1.f / 128.f) - mu * mu + 1e-5f);
            }
            #pragma unroll
            for (int i = 0; i < 4; i++) {
                int nrow = base + (mp * 2 + ml) * 16 + g * 4 + i;
                #pragma unroll
                for (int nb = 0; nb < 8; nb++) {
                    float v = (acc2[ml][nb][i] - muv[i]) * rsv[i] * gamv[nb] + btv[nb];
                    float pv = __shfl_xor(v, 1);
                    if (!(c15 & 1) && nrow < NNODES) {
                        int col = nb * 16 + c15;
                        u32* nlp = (u32*)(nl + (size_t)nrow * L + col);
                        u32 old = *nlp;
                        float r0 = h2f((u16)(old & 0xFFFFu)) + v;
                        float r1 = h2f((u16)(old >> 16)) + pv;
                        *nlp = (u32)f2h(r0) | ((u32)f2h(r1) << 16);
                    }
                }
            }
        }
    }
}

// ---------------------------------------------------------------------------
// Decoder: nl(fp16) -> 8 (swish) -> 15, scale by dt, write [TW,N,OUT] fp32
// ---------------------------------------------------------------------------
__global__ __launch_bounds__(256) void decode_kernel(
    const u16* __restrict__ nl,
    const float* __restrict__ w1, const float* __restrict__ b1,
    const float* __restrict__ w2, const float* __restrict__ b2,
    float* __restrict__ out)
{
    int n = blockIdx.x * blockDim.x + threadIdx.x;
    if (n >= NNODES) return;
    float h8[8];
    #pragma unroll
    for (int jj = 0; jj < 8; jj++) h8[jj] = b1[jj];
    const u16* row = nl + (size_t)n * L;
    for (int k = 0; k < L; k += 8) {
        float xv[8];
        load8h(row + k, xv);
        #pragma unroll
        for (int q = 0; q < 8; q++)
            #pragma unroll
            for (int jj = 0; jj < 8; jj++)
                h8[jj] += xv[q] * w1[(k + q) * 8 + jj];
    }
    #pragma unroll
    for (int jj = 0; jj < 8; jj++) { float v = h8[jj]; h8[jj] = v / (1.f + expf(-v)); }
    #pragma unroll
    for (int o15 = 0; o15 < 15; o15++) {
        float accv = b2[o15];
        #pragma unroll
        for (int jj = 0; jj < 8; jj++) accv += h8[jj] * w2[jj * 15 + o15];
        int tt = o15 / 3, oo = o15 - tt * 3;
        out[(size_t)tt * NNODES * 3 + (size_t)n * 3 + oo] = accv * (float)(tt + 1);
    }
}

// ---------------------------------------------------------------------------
extern "C" void kernel_launch(void* const* d_in, const int* in_sizes, int n_in,
                              void* d_out, int out_size, void* d_ws, size_t ws_size,
                              hipStream_t stream)
{
    // workspace layout (~267 MB)
    const size_t AG_B = (size_t)NNODES * L * 2;             //  25.6 MB
    const size_t EL_B = (size_t)NEDGES * L * 2;             // 204.8 MB
    const size_t NL_B = (size_t)NNODES * L * 2;             //  25.6 MB
    const size_t PE1_N = (size_t)15 * 8 * 12 * 64 * 8;      // u16 counts
    const size_t PE2_N = (size_t)15 * 8 * 4 * 64 * 8;
    const size_t PN1_N = (size_t)15 * 8 * 8 * 64 * 8;
    const size_t PN2_N = (size_t)15 * 8 * 4 * 64 * 8;
    const size_t PEE1_N = (size_t)8 * 64 * 8;               // ee layer1 (padded)
    const size_t PEE2_N = (size_t)8 * 4 * 64 * 8;           // ee layer2
    const size_t WPK_B = (PE1_N + PE2_N + PN1_N + PN2_N + PEE1_N + PEE2_N) * 2;
    const size_t SS_B  = (size_t)NEDGES * 4;                // ssorted
    const size_t RS_B  = (size_t)NEDGES * 4;                // rsorted
    const size_t CNT_B = (size_t)NNODES * 4;                // counts
    const size_t OFF_B = (size_t)NNODES * 4;                // offsets
    const size_t CUR_B = (size_t)NNODES * 4;                // cursor
    const size_t PAR_B = 2048;                              // partials (>=391*4)
    const size_t TOTAL = AG_B + EL_B + NL_B + WPK_B + SS_B + RS_B
                       + CNT_B + OFF_B + CUR_B + PAR_B;

    if (ws_size < TOTAL) {
        float val = 1000.0f + (float)((double)ws_size * 1e-6);
        diag_kernel<<<(out_size + 255) / 256, 256, 0, stream>>>((float*)d_out, out_size, val);
        return;
    }

    char* wsp = (char*)d_ws;
    u16* aggr = (u16*)wsp;                 wsp += AG_B;
    u16* el   = (u16*)wsp;                 wsp += EL_B;
    u16* nl   = (u16*)wsp;                 wsp += NL_B;
    u16* pe1  = (u16*)wsp;                 wsp += PE1_N * 2;
    u16* pe2  = (u16*)wsp;                 wsp += PE2_N * 2;
    u16* pn1  = (u16*)wsp;                 wsp += PN1_N * 2;
    u16* pn2  = (u16*)wsp;                 wsp += PN2_N * 2;
    u16* pee1 = (u16*)wsp;                 wsp += PEE1_N * 2;
    u16* pee2 = (u16*)wsp;                 wsp += PEE2_N * 2;
    int* ssorted = (int*)wsp;              wsp += SS_B;
    int* rsorted = (int*)wsp;              wsp += RS_B;
    u32* counts  = (u32*)wsp;              wsp += CNT_B;
    u32* offsets = (u32*)wsp;              wsp += OFF_B;
    u32* cursor  = (u32*)wsp;              wsp += CUR_B;
    u32* partials = (u32*)wsp;             wsp += PAR_B;
    float* out = (float*)d_out;

    const float* pvf       = (const float*)d_in[0];
    const float* matD      = (const float*)d_in[1];
    const float* matX      = (const float*)d_in[2];
    const int*   ntype     = (const int*)d_in[3];
    const float* mesh      = (const float*)d_in[4];
    const float* world     = (const float*)d_in[5];
    const int*   senders   = (const int*)d_in[6];
    const int*   receivers = (const int*)d_in[7];
    const float* nmean = (const float*)d_in[8];
    const float* nstd  = (const float*)d_in[9];
    const float* emean = (const float*)d_in[10];
    const float* estd  = (const float*)d_in[11];
    const float* ne_w1 = (const float*)d_in[12];
    const float* ne_b1 = (const float*)d_in[13];
    const float* ne_w2 = (const float*)d_in[14];
    const float* ne_b2 = (const float*)d_in[15];
    const float* ne_g  = (const float*)d_in[16];
    const float* ne_be = (const float*)d_in[17];
    const float* ee_w1 = (const float*)d_in[18];
    const float* ee_b1 = (const float*)d_in[19];
    const float* ee_w2 = (const float*)d_in[20];
    const float* ee_b2 = (const float*)d_in[21];
    const float* ee_g  = (const float*)d_in[22];
    const float* ee_be = (const float*)d_in[23];
    const float* blk_ew1 = (const float*)d_in[24];
    const float* blk_eb1 = (const float*)d_in[25];
    const float* blk_ew2 = (const float*)d_in[26];
    const float* blk_eb2 = (const float*)d_in[27];
    const float* blk_eg  = (const float*)d_in[28];
    const float* blk_ebt = (const float*)d_in[29];
    const float* blk_nw1 = (const float*)d_in[30];
    const float* blk_nb1 = (const float*)d_in[31];
    const float* blk_nw2 = (const float*)d_in[32];
    const float* blk_nb2 = (const float*)d_in[33];
    const float* blk_ng  = (const float*)d_in[34];
    const float* blk_nbt = (const float*)d_in[35];
    const float* dec_w1 = (const float*)d_in[36];
    const float* dec_b1 = (const float*)d_in[37];
    const float* dec_w2 = (const float*)d_in[38];
    const float* dec_b2 = (const float*)d_in[39];

    // --- counting sort of edges by receiver (one-time) ---
    zero_kernel<<<(int)((CNT_B / 16 + 255) / 256), 256, 0, stream>>>((uint4*)counts, (int)(CNT_B / 16));
    count_kernel<<<(NEDGES + 255) / 256, 256, 0, stream>>>(receivers, counts);
    scan_block_kernel<<<NBSCAN, 256, 0, stream>>>(counts, offsets, partials);
    scan_partials_kernel<<<1, 512, 0, stream>>>(partials);
    add_offsets_kernel<<<NBSCAN, 256, 0, stream>>>(offsets, partials, cursor);
    scatter_kernel<<<(NEDGES + 255) / 256, 256, 0, stream>>>(senders, receivers, cursor, ssorted, rsorted);

    // pack fp16 weights into B-fragment order
    pack_weights_kernel<<<(int)((15 * 8 * 12 * 64 + 255) / 256), 256, 0, stream>>>(
        blk_ew1, pe1, 384, 15);
    pack_weights_kernel<<<(int)((15 * 8 * 4 * 64 + 255) / 256), 256, 0, stream>>>(
        blk_ew2, pe2, 128, 15);
    pack_weights_kernel<<<(int)((15 * 8 * 8 * 64 + 255) / 256), 256, 0, stream>>>(
        blk_nw1, pn1, 256, 15);
    pack_weights_kernel<<<(int)((15 * 8 * 4 * 64 + 255) / 256), 256, 0, stream>>>(
        blk_nw2, pn2, 128, 15);
    pack_ee1_kernel<<<2, 256, 0, stream>>>(ee_w1, pee1);
    pack_weights_kernel<<<(int)((8 * 4 * 64 + 255) / 256), 256, 0, stream>>>(
        ee_w2, pee2, 128, 1);

    node_encode_kernel<<<(NNODES + 63) / 64, 256, 0, stream>>>(
        pvf, matD, matX, ntype, nmean, nstd,
        ne_w1, ne_b1, ne_w2, ne_b2, ne_g, ne_be, nl);
    edge_encode_kernel<<<NEDGES / 256, 256, 0, stream>>>(
        ssorted, rsorted, pvf, mesh, world, emean, estd,
        pee1, ee_b1, pee2, ee_b2, ee_g, ee_be, el);

    // one-time aggr zero; afterwards node_block re-zeroes for the next step
    const int nzero = NNODES * L * 2 / 16;
    zero_kernel<<<(nzero + 255) / 256, 256, 0, stream>>>((uint4*)aggr, nzero);

    for (int s = 0; s < 15; s++) {
        edge_block_kernel<<<NEDGES / 256, 256, 0, stream>>>(
            ssorted, rsorted, nl, el, aggr,
            pe1 + (size_t)s * 8 * 12 * 64 * 8, blk_eb1 + s * L,
            pe2 + (size_t)s * 8 * 4 * 64 * 8,  blk_eb2 + s * L,
            blk_eg + s * L, blk_ebt + s * L);
        node_block_kernel<<<(NNODES + 255) / 256, 256, 0, stream>>>(
            nl, aggr,
            pn1 + (size_t)s * 8 * 8 * 64 * 8, blk_nb1 + s * L,
            pn2 + (size_t)s * 8 * 4 * 64 * 8, blk_nb2 + s * L,
            blk_ng + s * L, blk_nbt + s * L);
    }

    decode_kernel<<<(NNODES + 255) / 256, 256, 0, stream>>>(
        nl, dec_w1, dec_b1, dec_w2, dec_b2, out);
}

// Round 18
// 6791.277 us; speedup vs baseline: 1.1940x; 1.0082x over previous
//
#include <hip/hip_runtime.h>
#include <math.h>

#define NNODES 100000
#define NEDGES 800000
#define L 128
#define NBSCAN ((NNODES + 255) / 256)   // 391 scan blocks

typedef unsigned short u16;
typedef unsigned int u32;
typedef unsigned short ushort8 __attribute__((ext_vector_type(8)));
typedef _Float16 f16x8 __attribute__((ext_vector_type(8)));
typedef __attribute__((ext_vector_type(4))) float f32x4;

// ---- conversions -----------------------------------------------------------
static __device__ __forceinline__ float h2f(u16 u) {       // fp16 -> f32
    _Float16 h;
    __builtin_memcpy(&h, &u, 2);
    return (float)h;
}
static __device__ __forceinline__ u16 f2h(float x) {       // f32 -> fp16 RNE
    _Float16 h = (_Float16)x;
    u16 u;
    __builtin_memcpy(&u, &h, 2);
    return u;
}
static __device__ __forceinline__ void load8h(const u16* p, float* d) {
    ushort8 v = *(const ushort8*)p;
    #pragma unroll
    for (int k = 0; k < 8; k++) d[k] = h2f(v[k]);
}
// HW packed fp16x2 atomic add (gfx90a+), no memory clobber (nothing here
// reads aggr; clobber would serialize the epilogue).
static __device__ __forceinline__ void atomic_pk_add_f16(u16* addr, u32 data) {
    asm volatile("global_atomic_pk_add_f16 %0, %1, off" :: "v"(addr), "v"(data));
}

// ---------------------------------------------------------------------------
__global__ __launch_bounds__(256) void zero_kernel(uint4* p, int n) {
    int i = blockIdx.x * 256 + threadIdx.x;
    if (i < n) p[i] = make_uint4(0u, 0u, 0u, 0u);
}

__global__ __launch_bounds__(256) void diag_kernel(float* out, int n, float val) {
    int i = blockIdx.x * 256 + threadIdx.x;
    if (i < n) out[i] = val;
}

// ---------------------------------------------------------------------------
// Counting sort of edges by receiver: counts -> scan -> scatter.
// ---------------------------------------------------------------------------
__global__ __launch_bounds__(256) void count_kernel(
    const int* __restrict__ receivers, u32* __restrict__ counts)
{
    int e = blockIdx.x * 256 + threadIdx.x;
    if (e < NEDGES) atomicAdd(&counts[receivers[e]], 1u);
}

__global__ __launch_bounds__(256) void scan_block_kernel(
    const u32* __restrict__ counts, u32* __restrict__ offsets,
    u32* __restrict__ partials)
{
    __shared__ u32 sh[256];
    int i = blockIdx.x * 256 + threadIdx.x;
    u32 c = (i < NNODES) ? counts[i] : 0u;
    sh[threadIdx.x] = c;
    __syncthreads();
    #pragma unroll
    for (int d = 1; d < 256; d <<= 1) {
        u32 v = (threadIdx.x >= d) ? sh[threadIdx.x - d] : 0u;
        __syncthreads();
        sh[threadIdx.x] += v;
        __syncthreads();
    }
    if (i < NNODES) offsets[i] = sh[threadIdx.x] - c;   // excl within block
    if (threadIdx.x == 255) partials[blockIdx.x] = sh[255];
}

__global__ __launch_bounds__(512) void scan_partials_kernel(u32* __restrict__ partials)
{
    __shared__ u32 sh[512];
    int x = threadIdx.x;
    u32 c = (x < NBSCAN) ? partials[x] : 0u;
    sh[x] = c;
    __syncthreads();
    #pragma unroll
    for (int d = 1; d < 512; d <<= 1) {
        u32 v = (x >= d) ? sh[x - d] : 0u;
        __syncthreads();
        sh[x] += v;
        __syncthreads();
    }
    if (x < NBSCAN) partials[x] = sh[x] - c;            // exclusive
}

__global__ __launch_bounds__(256) void add_offsets_kernel(
    u32* __restrict__ offsets, const u32* __restrict__ partials,
    u32* __restrict__ cursor)
{
    int i = blockIdx.x * 256 + threadIdx.x;
    if (i < NNODES) {
        u32 v = offsets[i] + partials[blockIdx.x];
        offsets[i] = v;
        cursor[i] = v;
    }
}

__global__ __launch_bounds__(256) void scatter_kernel(
    const int* __restrict__ senders, const int* __restrict__ receivers,
    u32* __restrict__ cursor, int* __restrict__ ssorted, int* __restrict__ rsorted)
{
    int e = blockIdx.x * 256 + threadIdx.x;
    if (e < NEDGES) {
        int r = receivers[e];
        u32 pos = atomicAdd(&cursor[r], 1u);
        ssorted[pos] = senders[e];
        rsorted[pos] = r;
    }
}

// ---------------------------------------------------------------------------
// Weight pre-pack into MFMA B-fragment order, single fp16.
// ---------------------------------------------------------------------------
__global__ __launch_bounds__(256) void pack_weights_kernel(
    const float* __restrict__ src, u16* __restrict__ dst, int K, int nsteps)
{
    int idx = blockIdx.x * 256 + threadIdx.x;
    int nkk = K >> 5;
    int total = nsteps * 8 * nkk * 64;
    if (idx >= total) return;
    int lane = idx & 63;
    int rest = idx >> 6;
    int kk = rest % nkk; rest /= nkk;
    int nb = rest & 7;
    int s = rest >> 3;
    int c15 = lane & 15, gg = lane >> 4;
    const float* w = src + (size_t)s * K * 128;
    u16 out[8];
    #pragma unroll
    for (int j = 0; j < 8; j++) {
        int k = kk * 32 + gg * 8 + j;
        out[j] = f2h(w[(size_t)k * 128 + nb * 16 + c15]);
    }
    *(ushort8*)(dst + (size_t)idx * 8) = *(ushort8*)out;
}

// pack edge-encoder layer1 (7x128), K padded to 32 with zero rows
__global__ __launch_bounds__(256) void pack_ee1_kernel(
    const float* __restrict__ src, u16* __restrict__ dst)
{
    int idx = blockIdx.x * 256 + threadIdx.x;
    if (idx >= 8 * 64) return;
    int lane = idx & 63, nb = idx >> 6;
    int c15 = lane & 15, gg = lane >> 4;
    u16 out[8];
    #pragma unroll
    for (int j = 0; j < 8; j++) {
        int k = gg * 8 + j;
        out[j] = (k < 7) ? f2h(src[(size_t)k * 128 + nb * 16 + c15]) : (u16)0;
    }
    *(ushort8*)(dst + (size_t)idx * 8) = *(ushort8*)out;
}

// ---------------------------------------------------------------------------
// Node encoder: feats(6) -> 128 -> 128 -> LN -> fp16 nl  (64 nodes / block)
// ---------------------------------------------------------------------------
__global__ __launch_bounds__(256) void node_encode_kernel(
    const float* __restrict__ pvf, const float* __restrict__ matD,
    const float* __restrict__ matX, const int* __restrict__ ntype,
    const float* __restrict__ nmean, const float* __restrict__ nstd,
    const float* __restrict__ w1, const float* __restrict__ b1,
    const float* __restrict__ w2, const float* __restrict__ b2,
    const float* __restrict__ g, const float* __restrict__ be,
    u16* __restrict__ nl)
{
    __shared__ float xs[64][8];
    __shared__ float h[64][132];
    const int t = threadIdx.x;
    const int base = blockIdx.x * 64;
    if (t < 64) {
        int n = base + t;
        if (n < NNODES) {
            int nt = ntype[n];
            float f[6];
            f[0] = pvf[n]; f[1] = matD[n]; f[2] = matX[n];
            f[3] = (nt == 0) ? 1.f : 0.f;
            f[4] = (nt == 1) ? 1.f : 0.f;
            f[5] = (nt == 2) ? 1.f : 0.f;
            #pragma unroll
            for (int k = 0; k < 6; k++) xs[t][k] = (f[k] - nmean[k]) / nstd[k];
        } else {
            #pragma unroll
            for (int k = 0; k < 6; k++) xs[t][k] = 0.f;
        }
    }
    __syncthreads();
    const int j = t & 127, half = t >> 7;
    for (int i = 0; i < 32; i++) {
        int e = half * 32 + i;
        float acc = b1[j];
        #pragma unroll
        for (int k = 0; k < 6; k++) acc += xs[e][k] * w1[k * L + j];
        h[e][j] = fmaxf(acc, 0.f);
    }
    __syncthreads();
    float acc2[32];
    #pragma unroll
    for (int i = 0; i < 32; i++) acc2[i] = b2[j];
    for (int k4 = 0; k4 < 32; k4++) {
        const float* wp = w2 + k4 * 4 * L + j;
        float wa = wp[0], wb = wp[L], wc = wp[2 * L], wd = wp[3 * L];
        #pragma unroll
        for (int i = 0; i < 32; i++) {
            const float4 xv = *(const float4*)&h[half * 32 + i][k4 * 4];
            acc2[i] += xv.x * wa + xv.y * wb + xv.z * wc + xv.w * wd;
        }
    }
    __syncthreads();
    #pragma unroll
    for (int i = 0; i < 32; i++) h[half * 32 + i][j] = fmaxf(acc2[i], 0.f);
    __syncthreads();
    {
        const int e = t >> 2, tg = t & 3;
        float sum = 0.f, sq = 0.f;
        #pragma unroll
        for (int jj = 0; jj < 32; jj++) { float v = h[e][tg * 32 + jj]; sum += v; sq += v * v; }
        sum += __shfl_xor(sum, 1); sq += __shfl_xor(sq, 1);
        sum += __shfl_xor(sum, 2); sq += __shfl_xor(sq, 2);
        float mu = sum * (1.f / 128.f);
        float rstd = rsqrtf(sq * (1.f / 128.f) - mu * mu + 1e-5f);
        int n = base + e;
        if (n < NNODES) {
            u32* nrow = (u32*)(nl + (size_t)n * L) + tg * 16;
            #pragma unroll
            for (int p = 0; p < 16; p++) {
                int f0 = tg * 32 + 2 * p;
                float v0 = (h[e][f0] - mu) * rstd * g[f0] + be[f0];
                float v1 = (h[e][f0 + 1] - mu) * rstd * g[f0 + 1] + be[f0 + 1];
                nrow[p] = (u32)f2h(v0) | ((u32)f2h(v1) << 16);
            }
        }
    }
}

// ---------------------------------------------------------------------------
// MFMA edge encoder (sorted edge space): feats(7, padded to K=32) -> 128
// -> 128 -> LN -> fp16 el.  256 edges/block, 4 waves, wave = 64 rows.
// ---------------------------------------------------------------------------
__global__ __launch_bounds__(256, 2) void edge_encode_kernel(
    const int* __restrict__ ssorted, const int* __restrict__ rsorted,
    const float* __restrict__ pvf, const float* __restrict__ mesh,
    const float* __restrict__ world,
    const float* __restrict__ emean, const float* __restrict__ estd,
    const u16* __restrict__ wp1, const float* __restrict__ b1,
    const u16* __restrict__ wp2, const float* __restrict__ b2,
    const float* __restrict__ gamma, const float* __restrict__ beta,
    u16* __restrict__ el)
{
    __shared__ __align__(16) u16 hbuf[4][2][4][64][8];   // 32 KB
    const int t = threadIdx.x;
    const int wid = t >> 6, lane = t & 63;
    const int c15 = lane & 15, g = lane >> 4;
    const int base = blockIdx.x * 256 + wid * 64;   // E % 256 == 0

    // A-fragments: only the g==0 k-chunk carries the 7 features (rest zero)
    f16x8 a[4];
    #pragma unroll
    for (int m = 0; m < 4; m++) {
        f16x8 v;
        #pragma unroll
        for (int k = 0; k < 8; k++) v[k] = (_Float16)0.f;
        if (g == 0) {
            int e = base + m * 16 + c15;
            int s = ssorted[e], r = rsorted[e];
            float rmx = mesh[s * 2] - mesh[r * 2];
            float rmy = mesh[s * 2 + 1] - mesh[r * 2 + 1];
            float dm = sqrtf(rmx * rmx + rmy * rmy);
            float rwx = world[s * 2] - world[r * 2];
            float rwy = world[s * 2 + 1] - world[r * 2 + 1];
            float dw = sqrtf(rwx * rwx + rwy * rwy);
            float pg = pvf[s] - pvf[r];
            float f[7] = {rmx, rmy, dm, rwx, rwy, dw, pg};
            #pragma unroll
            for (int k = 0; k < 7; k++)
                v[k] = (_Float16)((f[k] - emean[k]) / estd[k]);
        }
        a[m] = v;
    }

    // ---- layer 1: single k-step (K=32 padded) ----
    f32x4 acc[8][4];
    #pragma unroll
    for (int nb = 0; nb < 8; nb++) {
        float bv = b1[nb * 16 + c15];
        #pragma unroll
        for (int m = 0; m < 4; m++) acc[nb][m] = (f32x4){bv, bv, bv, bv};
    }
    #pragma unroll
    for (int nb = 0; nb < 8; nb++) {
        f16x8 b = *(const f16x8*)(wp1 + ((size_t)(nb * 64 + lane)) * 8);
        #pragma unroll
        for (int m = 0; m < 4; m++)
            acc[nb][m] = __builtin_amdgcn_mfma_f32_16x16x32_f16(a[m], b, acc[nb][m], 0, 0, 0);
    }

    // ---- layer 2 in m-pairs ----
    float gamv[8], btv[8];
    #pragma unroll
    for (int nb = 0; nb < 8; nb++) {
        gamv[nb] = gamma[nb * 16 + c15];
        btv[nb] = beta[nb * 16 + c15];
    }
    #pragma unroll
    for (int mp = 0; mp < 2; mp++) {
        #pragma unroll
        for (int ml = 0; ml < 2; ml++) {
            int m = mp * 2 + ml;
            #pragma unroll
            for (int nb = 0; nb < 8; nb++) {
                int kk2 = nb >> 1;
                int sub = ((nb & 1) << 1) | (c15 >> 3);
                int jj = c15 & 7;
                #pragma unroll
                for (int i = 0; i < 4; i++) {
                    float v = fmaxf(acc[nb][m][i], 0.f);
                    hbuf[wid][ml][kk2][g * 4 + i + 16 * sub][jj] = f2h(v);
                }
            }
        }
        f32x4 acc2[2][8];
        #pragma unroll
        for (int nb = 0; nb < 8; nb++) {
            float bv = b2[nb * 16 + c15];
            acc2[0][nb] = (f32x4){bv, bv, bv, bv};
            acc2[1][nb] = (f32x4){bv, bv, bv, bv};
        }
        #pragma unroll
        for (int kk = 0; kk < 4; kk++) {
            f16x8 a0 = *(const f16x8*)&hbuf[wid][0][kk][lane][0];
            f16x8 a1 = *(const f16x8*)&hbuf[wid][1][kk][lane][0];
            #pragma unroll
            for (int nb = 0; nb < 8; nb++) {
                f16x8 b = *(const f16x8*)(wp2 + ((size_t)(nb * 4 + kk) * 64 + lane) * 8);
                acc2[0][nb] = __builtin_amdgcn_mfma_f32_16x16x32_f16(a0, b, acc2[0][nb], 0, 0, 0);
                acc2[1][nb] = __builtin_amdgcn_mfma_f32_16x16x32_f16(a1, b, acc2[1][nb], 0, 0, 0);
            }
        }
        #pragma unroll
        for (int ml = 0; ml < 2; ml++) {
            float muv[4], rsv[4];
            #pragma unroll
            for (int i = 0; i < 4; i++) {
                float p = 0.f, q = 0.f;
                #pragma unroll
                for (int nb = 0; nb < 8; nb++) {
                    float v = fmaxf(acc2[ml][nb][i], 0.f);
                    acc2[ml][nb][i] = v;
                    p += v; q += v * v;
                }
                p += __shfl_xor(p, 1); q += __shfl_xor(q, 1);
                p += __shfl_xor(p, 2); q += __shfl_xor(q, 2);
                p += __shfl_xor(p, 4); q += __shfl_xor(q, 4);
                p += __shfl_xor(p, 8); q += __shfl_xor(q, 8);
                float mu = p * (1.f / 128.f);
                muv[i] = mu;
                rsv[i] = rsqrtf(q * (1.f / 128.f) - mu * mu + 1e-5f);
            }
            #pragma unroll
            for (int i = 0; i < 4; i++) {
                int erow = base + (mp * 2 + ml) * 16 + g * 4 + i;
                #pragma unroll
                for (int nb = 0; nb < 8; nb++) {
                    float v = (acc2[ml][nb][i] - muv[i]) * rsv[i] * gamv[nb] + btv[nb];
                    float pv = __shfl_xor(v, 1);
                    if (!(c15 & 1)) {
                        *(u32*)(el + (size_t)erow * L + nb * 16 + c15) =
                            (u32)f2h(v) | ((u32)f2h(pv) << 16);
                    }
                }
            }
        }
    }
}

// A-gather for edge layer-1, k-step nk (0..11), into ab[slot]
#define EDGE_LOAD_A(nk, slot)                                                     \
    {                                                                             \
        _Pragma("unroll")                                                         \
        for (int m = 0; m < 4; m++) {                                             \
            const u16* ap;                                                        \
            if ((nk) < 4)      ap = nl + (size_t)sA[m] * L + (nk) * 32 + g * 8;   \
            else if ((nk) < 8) ap = nl + (size_t)rA[m] * L + ((nk) - 4) * 32 + g * 8; \
            else               ap = el + (size_t)(base + m * 16 + c15) * L + ((nk) - 8) * 32 + g * 8; \
            ab[slot][m] = *(const f16x8*)ap;                                      \
        }                                                                         \
    }

#define NODE_LOAD_A(nk, slot)                                                     \
    {                                                                             \
        _Pragma("unroll")                                                         \
        for (int m = 0; m < 4; m++) {                                             \
            const u16* ap = ((nk) < 4) ? (nl + (size_t)rowL[m] * L + (nk) * 32 + g * 8) \
                                       : (aggr + (size_t)rowL[m] * L + ((nk) - 4) * 32 + g * 8); \
            ab[slot][m] = *(const f16x8*)ap;                                      \
        }                                                                         \
    }

// lgkm-only barrier: LDS ops drained, global loads stay in flight
#define LGKM_BARRIER()                                          \
    asm volatile("s_waitcnt lgkmcnt(0)" ::: "memory");          \
    __builtin_amdgcn_sched_barrier(0);                          \
    __builtin_amdgcn_s_barrier();

// ---------------------------------------------------------------------------
// fp16-MFMA GraphNetBlock edge update (sorted edge space). T14 reg-staged
// weight pipeline + run-merged aggr atomics + T5 setprio + batched epilogue
// + T1 bijective XCD-chunked block swizzle (m204: nwg % 8 != 0 safe) so each
// XCD owns a contiguous range of sorted edges -> aggr lines stay in one L2.
// ---------------------------------------------------------------------------
__global__ __launch_bounds__(256, 2) void edge_block_kernel(
    const int* __restrict__ ssorted, const int* __restrict__ rsorted,
    const u16* __restrict__ nl, u16* __restrict__ el, u16* __restrict__ aggr,
    const u16* __restrict__ wp1, const float* __restrict__ b1,
    const u16* __restrict__ wp2, const float* __restrict__ b2,
    const float* __restrict__ gamma, const float* __restrict__ beta)
{
    __shared__ __align__(16) u16 wbuf[2][8][64][8];      // 16 KB B dbuf
    __shared__ __align__(16) u16 hbuf[4][2][4][64][8];   // 32 KB h-frag
    const int t = threadIdx.x;
    const int wid = t >> 6, lane = t & 63;
    const int c15 = lane & 15, g = lane >> 4;
    // T1: round-robin dispatch -> contiguous per-XCD chunks (bijective, m204)
    const int nwg = NEDGES / 256;            // 3125
    const int q = nwg >> 3, r = nwg & 7;     // 390, 5
    const int xcd = blockIdx.x & 7, idx = blockIdx.x >> 3;
    const int bid = (xcd < r ? xcd * (q + 1) : r * (q + 1) + (xcd - r) * q) + idx;
    const int base = bid * 256 + wid * 64;   // E % 256 == 0

    int sA[4], rA[4];
    #pragma unroll
    for (int m = 0; m < 4; m++) {
        sA[m] = ssorted[base + m * 16 + c15];
        rA[m] = rsorted[base + m * 16 + c15];
    }

    // ---- layer 1: K = 384 (12 k-steps), M = 64, T14 pipeline ----
    f32x4 acc[8][4];
    #pragma unroll
    for (int nb = 0; nb < 8; nb++) {
        float bv = b1[nb * 16 + c15];
        #pragma unroll
        for (int m = 0; m < 4; m++) acc[nb][m] = (f32x4){bv, bv, bv, bv};
    }
    f16x8 ab[2][4];
    f16x8 w0, w1;
    w0 = *(const f16x8*)(wp1 + ((size_t)((2 * wid) * 12 + 0) * 64 + lane) * 8);
    w1 = *(const f16x8*)(wp1 + ((size_t)((2 * wid + 1) * 12 + 0) * 64 + lane) * 8);
    EDGE_LOAD_A(0, 0);
    *(f16x8*)&wbuf[0][2 * wid][lane][0] = w0;
    *(f16x8*)&wbuf[0][2 * wid + 1][lane][0] = w1;
    LGKM_BARRIER();

    #pragma unroll
    for (int kk = 0; kk < 12; kk++) {
        if (kk < 11) {
            w0 = *(const f16x8*)(wp1 + ((size_t)((2 * wid) * 12 + kk + 1) * 64 + lane) * 8);
            w1 = *(const f16x8*)(wp1 + ((size_t)((2 * wid + 1) * 12 + kk + 1) * 64 + lane) * 8);
            EDGE_LOAD_A(kk + 1, (kk + 1) & 1);
        }
        __builtin_amdgcn_s_setprio(1);
        #pragma unroll
        for (int nb = 0; nb < 8; nb++) {
            f16x8 b = *(const f16x8*)&wbuf[kk & 1][nb][lane][0];
            #pragma unroll
            for (int m = 0; m < 4; m++)
                acc[nb][m] = __builtin_amdgcn_mfma_f32_16x16x32_f16(ab[kk & 1][m], b, acc[nb][m], 0, 0, 0);
        }
        __builtin_amdgcn_s_setprio(0);
        if (kk < 11) {
            *(f16x8*)&wbuf[(kk + 1) & 1][2 * wid][lane][0] = w0;
            *(f16x8*)&wbuf[(kk + 1) & 1][2 * wid + 1][lane][0] = w1;
            LGKM_BARRIER();
        }
    }

    // ---- layer 2 in m-pairs (B from global/L2) ----
    float gamv[8], btv[8];
    #pragma unroll
    for (int nb = 0; nb < 8; nb++) {
        gamv[nb] = gamma[nb * 16 + c15];
        btv[nb] = beta[nb * 16 + c15];
    }
    #pragma unroll
    for (int mp = 0; mp < 2; mp++) {
        #pragma unroll
        for (int ml = 0; ml < 2; ml++) {
            int m = mp * 2 + ml;
            #pragma unroll
            for (int nb = 0; nb < 8; nb++) {
                int kk2 = nb >> 1;
                int sub = ((nb & 1) << 1) | (c15 >> 3);
                int jj = c15 & 7;
                #pragma unroll
                for (int i = 0; i < 4; i++) {
                    float v = fmaxf(acc[nb][m][i], 0.f);
                    hbuf[wid][ml][kk2][g * 4 + i + 16 * sub][jj] = f2h(v);
                }
            }
        }
        f32x4 acc2[2][8];
        #pragma unroll
        for (int nb = 0; nb < 8; nb++) {
            float bv = b2[nb * 16 + c15];
            acc2[0][nb] = (f32x4){bv, bv, bv, bv};
            acc2[1][nb] = (f32x4){bv, bv, bv, bv};
        }
        __builtin_amdgcn_s_setprio(1);
        #pragma unroll
        for (int kk = 0; kk < 4; kk++) {
            f16x8 a0 = *(const f16x8*)&hbuf[wid][0][kk][lane][0];
            f16x8 a1 = *(const f16x8*)&hbuf[wid][1][kk][lane][0];
            #pragma unroll
            for (int nb = 0; nb < 8; nb++) {
                f16x8 b = *(const f16x8*)(wp2 + ((size_t)(nb * 4 + kk) * 64 + lane) * 8);
                acc2[0][nb] = __builtin_amdgcn_mfma_f32_16x16x32_f16(a0, b, acc2[0][nb], 0, 0, 0);
                acc2[1][nb] = __builtin_amdgcn_mfma_f32_16x16x32_f16(a1, b, acc2[1][nb], 0, 0, 0);
            }
        }
        __builtin_amdgcn_s_setprio(0);
        // ---- relu + LN + residual + run-merged aggr atomics, per m ----
        #pragma unroll
        for (int ml = 0; ml < 2; ml++) {
            const int slot = mp * 2 + ml;
            float muv[4], rsv[4];
            #pragma unroll
            for (int i = 0; i < 4; i++) {
                float p = 0.f, q2 = 0.f;
                #pragma unroll
                for (int nb = 0; nb < 8; nb++) {
                    float v = fmaxf(acc2[ml][nb][i], 0.f);
                    acc2[ml][nb][i] = v;
                    p += v; q2 += v * v;
                }
                p += __shfl_xor(p, 1); q2 += __shfl_xor(q2, 1);
                p += __shfl_xor(p, 2); q2 += __shfl_xor(q2, 2);
                p += __shfl_xor(p, 4); q2 += __shfl_xor(q2, 4);
                p += __shfl_xor(p, 8); q2 += __shfl_xor(q2, 8);
                float mu = p * (1.f / 128.f);
                muv[i] = mu;
                rsv[i] = rsqrtf(q2 * (1.f / 128.f) - mu * mu + 1e-5f);
            }
            float av[8], apv[8];
            #pragma unroll
            for (int nb = 0; nb < 8; nb++) { av[nb] = 0.f; apv[nb] = 0.f; }
            int cur = rsorted[base + slot * 16 + g * 4];
            #pragma unroll
            for (int i = 0; i < 4; i++) {
                int erow = base + slot * 16 + g * 4 + i;
                int ri = (i == 0) ? cur : rsorted[erow];
                float vv[8], pp[8];
                #pragma unroll
                for (int nb = 0; nb < 8; nb++) {
                    float v = (acc2[ml][nb][i] - muv[i]) * rsv[i] * gamv[nb] + btv[nb];
                    vv[nb] = v;
                    pp[nb] = __shfl_xor(v, 1);
                }
                u32 olds[8];
                if (!(c15 & 1)) {
                    #pragma unroll
                    for (int nb = 0; nb < 8; nb++)
                        olds[nb] = *(const u32*)(el + (size_t)erow * L + nb * 16 + c15);
                }
                if (ri != cur) {
                    #pragma unroll
                    for (int nb = 0; nb < 8; nb++) {
                        if (!(c15 & 1)) {
                            u32 add = (u32)f2h(av[nb]) | ((u32)f2h(apv[nb]) << 16);
                            atomic_pk_add_f16(aggr + (size_t)cur * L + nb * 16 + c15, add);
                        }
                        av[nb] = 0.f; apv[nb] = 0.f;
                    }
                    cur = ri;
                }
                #pragma unroll
                for (int nb = 0; nb < 8; nb++) {
                    av[nb] += vv[nb];
                    apv[nb] += pp[nb];
                    if (!(c15 & 1)) {
                        float r0 = h2f((u16)(olds[nb] & 0xFFFFu)) + vv[nb];
                        float r1 = h2f((u16)(olds[nb] >> 16)) + pp[nb];
                        *(u32*)(el + (size_t)erow * L + nb * 16 + c15) =
                            (u32)f2h(r0) | ((u32)f2h(r1) << 16);
                    }
                }
            }
            #pragma unroll
            for (int nb = 0; nb < 8; nb++) {
                if (!(c15 & 1)) {
                    u32 add = (u32)f2h(av[nb]) | ((u32)f2h(apv[nb]) << 16);
                    atomic_pk_add_f16(aggr + (size_t)cur * L + nb * 16 + c15, add);
                }
            }
        }
    }
}

// ---------------------------------------------------------------------------
// fp16-MFMA GraphNetBlock node update, T14 pipeline like edge_block.
// Also re-zeroes the aggr rows it consumed (fused zero for next step).
// ---------------------------------------------------------------------------
__global__ __launch_bounds__(256, 2) void node_block_kernel(
    u16* __restrict__ nl, u16* __restrict__ aggr,
    const u16* __restrict__ wp1, const float* __restrict__ b1,
    const u16* __restrict__ wp2, const float* __restrict__ b2,
    const float* __restrict__ gamma, const float* __restrict__ beta)
{
    __shared__ __align__(16) u16 wbuf[2][8][64][8];      // 16 KB
    __shared__ __align__(16) u16 hbuf[4][2][4][64][8];   // 32 KB
    const int t = threadIdx.x;
    const int wid = t >> 6, lane = t & 63;
    const int c15 = lane & 15, g = lane >> 4;
    const int base = blockIdx.x * 256 + wid * 64;

    int rowL[4];
    #pragma unroll
    for (int m = 0; m < 4; m++) {
        int r = base + m * 16 + c15;
        rowL[m] = r < NNODES ? r : 0;
    }

    f32x4 acc[8][4];
    #pragma unroll
    for (int nb = 0; nb < 8; nb++) {
        float bv = b1[nb * 16 + c15];
        #pragma unroll
        for (int m = 0; m < 4; m++) acc[nb][m] = (f32x4){bv, bv, bv, bv};
    }
    f16x8 ab[2][4];
    f16x8 w0, w1;
    w0 = *(const f16x8*)(wp1 + ((size_t)((2 * wid) * 8 + 0) * 64 + lane) * 8);
    w1 = *(const f16x8*)(wp1 + ((size_t)((2 * wid + 1) * 8 + 0) * 64 + lane) * 8);
    NODE_LOAD_A(0, 0);
    *(f16x8*)&wbuf[0][2 * wid][lane][0] = w0;
    *(f16x8*)&wbuf[0][2 * wid + 1][lane][0] = w1;
    LGKM_BARRIER();

    #pragma unroll
    for (int kk = 0; kk < 8; kk++) {
        if (kk < 7) {
            w0 = *(const f16x8*)(wp1 + ((size_t)((2 * wid) * 8 + kk + 1) * 64 + lane) * 8);
            w1 = *(const f16x8*)(wp1 + ((size_t)((2 * wid + 1) * 8 + kk + 1) * 64 + lane) * 8);
            NODE_LOAD_A(kk + 1, (kk + 1) & 1);
        }
        __builtin_amdgcn_s_setprio(1);
        #pragma unroll
        for (int nb = 0; nb < 8; nb++) {
            f16x8 b = *(const f16x8*)&wbuf[kk & 1][nb][lane][0];
            #pragma unroll
            for (int m = 0; m < 4; m++)
                acc[nb][m] = __builtin_amdgcn_mfma_f32_16x16x32_f16(ab[kk & 1][m], b, acc[nb][m], 0, 0, 0);
        }
        __builtin_amdgcn_s_setprio(0);
        if (kk < 7) {
            *(f16x8*)&wbuf[(kk + 1) & 1][2 * wid][lane][0] = w0;
            *(f16x8*)&wbuf[(kk + 1) & 1][2 * wid + 1][lane][0] = w1;
            LGKM_BARRIER();
        }
    }

    // fused aggr re-zero
    {
        const uint4 z4 = make_uint4(0u, 0u, 0u, 0u);
        #pragma unroll
        for (int m = 0; m < 4; m++) {
            int r = base + m * 16 + c15;
            if (r < NNODES) {
                #pragma unroll
                for (int kk = 0; kk < 4; kk++)
                    *(uint4*)(aggr + (size_t)r * L + kk * 32 + g * 8) = z4;
            }
        }
    }

    float gamv[8], btv[8];
    #pragma unroll
    for (int nb = 0; nb < 8; nb++) {
        gamv[nb] = gamma[nb * 16 + c15];
        btv[nb] = beta[nb * 16 + c15];
    }
    #pragma unroll
    for (int mp = 0; mp < 2; mp++) {
        #pragma unroll
        for (int ml = 0; ml < 2; ml++) {
            int m = mp * 2 + ml;
            #pragma unroll
            for (int nb = 0; nb < 8; nb++) {
                int kk2 = nb >> 1;
                int sub = ((nb & 1) << 1) | (c15 >> 3);
                int jj = c15 & 7;
                #pragma unroll
                for (int i = 0; i < 4; i++) {
                    float v = fmaxf(acc[nb][m][i], 0.f);
                    hbuf[wid][ml][kk2][g * 4 + i + 16 * sub][jj] = f2h(v);
                }
            }
        }
        f32x4 acc2[2][8];
        #pragma unroll
        for (int nb = 0; nb < 8; nb++) {
            float bv = b2[nb * 16 + c15];
            acc2[0][nb] = (f32x4){bv, bv, bv, bv};
            acc2[1][nb] = (f32x4){bv, bv, bv, bv};
        }
        __builtin_amdgcn_s_setprio(1);
        #pragma unroll
        for (int kk = 0; kk < 4; kk++) {
            f16x8 a0 = *(const f16x8*)&hbuf[wid][0][kk][lane][0];
            f16x8 a1 = *(const f16x8*)&hbuf[wid][1][kk][lane][0];
            #pragma unroll
            for (int nb = 0; nb < 8; nb++) {
                f16x8 b = *(const f16x8*)(wp2 + ((size_t)(nb * 4 + kk) * 64 + lane) * 8);
                acc2[0][nb] = __builtin_amdgcn_mfma_f32_16x16x32_f16(a0, b, acc2[0][nb], 0, 0, 0);
                acc2[1][nb] = __builtin_amdgcn_mfma_f32_16x16x32_f16(a1, b, acc2[1][nb], 0, 0, 0);
            }
        }
        __builtin_amdgcn_s_setprio(0);
        #pragma unroll
        for (int ml = 0; ml < 2; ml++) {
            float muv[4], rsv[4];
            #pragma unroll
            for (int i = 0; i < 4; i++) {
                float p = 0.f, q2 = 0.f;
                #pragma unroll
                for (int nb = 0; nb < 8; nb++) {
                    float v = fmaxf(acc2[ml][nb][i], 0.f);
                    acc2[ml][nb][i] = v;
                    p += v; q2 += v * v;
                }
                p += __shfl_xor(p, 1); q2 += __shfl_xor(q2, 1);
                p += __shfl_xor(p, 2); q2 += __shfl_xor(q2, 2);
                p += __shfl_xor(p, 4); q2 += __shfl_xor(q2, 4);
                p += __shfl_xor(p, 8); q2 += __shfl_xor(q2, 8);
                float mu = p * (1.f / 128.f);
                muv[i] = mu;
                rsv[i] = rsqrtf(q2 * (1.f / 128.f) - mu * mu + 1e-5f);
            }
            #pragma unroll
            for (int i = 0; i < 4; i++) {
                int nrow = base + (mp * 2 + ml) * 16 + g * 4 + i;
                #pragma unroll
                for (int nb = 0; nb < 8; nb++) {
                    float v = (acc2[ml][nb][i] - muv[i]) * rsv[i] * gamv[nb] + btv[nb];
                    float pv = __shfl_xor(v, 1);
                    if (!(c15 & 1) && nrow < NNODES) {
                        int col = nb * 16 + c15;
                        u32* nlp = (u32*)(nl + (size_t)nrow * L + col);
                        u32 old = *nlp;
                        float r0 = h2f((u16)(old & 0xFFFFu)) + v;
                        float r1 = h2f((u16)(old >> 16)) + pv;
                        *nlp = (u32)f2h(r0) | ((u32)f2h(r1) << 16);
                    }
                }
            }
        }
    }
}

// ---------------------------------------------------------------------------
// Decoder: nl(fp16) -> 8 (swish) -> 15, scale by dt, write [TW,N,OUT] fp32
// ---------------------------------------------------------------------------
__global__ __launch_bounds__(256) void decode_kernel(
    const u16* __restrict__ nl,
    const float* __restrict__ w1, const float* __restrict__ b1,
    const float* __restrict__ w2, const float* __restrict__ b2,
    float* __restrict__ out)
{
    int n = blockIdx.x * blockDim.x + threadIdx.x;
    if (n >= NNODES) return;
    float h8[8];
    #pragma unroll
    for (int jj = 0; jj < 8; jj++) h8[jj] = b1[jj];
    const u16* row = nl + (size_t)n * L;
    for (int k = 0; k < L; k += 8) {
        float xv[8];
        load8h(row + k, xv);
        #pragma unroll
        for (int q = 0; q < 8; q++)
            #pragma unroll
            for (int jj = 0; jj < 8; jj++)
                h8[jj] += xv[q] * w1[(k + q) * 8 + jj];
    }
    #pragma unroll
    for (int jj = 0; jj < 8; jj++) { float v = h8[jj]; h8[jj] = v / (1.f + expf(-v)); }
    #pragma unroll
    for (int o15 = 0; o15 < 15; o15++) {
        float accv = b2[o15];
        #pragma unroll
        for (int jj = 0; jj < 8; jj++) accv += h8[jj] * w2[jj * 15 + o15];
        int tt = o15 / 3, oo = o15 - tt * 3;
        out[(size_t)tt * NNODES * 3 + (size_t)n * 3 + oo] = accv * (float)(tt + 1);
    }
}

// ---------------------------------------------------------------------------
extern "C" void kernel_launch(void* const* d_in, const int* in_sizes, int n_in,
                              void* d_out, int out_size, void* d_ws, size_t ws_size,
                              hipStream_t stream)
{
    // workspace layout (~267 MB)
    const size_t AG_B = (size_t)NNODES * L * 2;             //  25.6 MB
    const size_t EL_B = (size_t)NEDGES * L * 2;             // 204.8 MB
    const size_t NL_B = (size_t)NNODES * L * 2;             //  25.6 MB
    const size_t PE1_N = (size_t)15 * 8 * 12 * 64 * 8;      // u16 counts
    const size_t PE2_N = (size_t)15 * 8 * 4 * 64 * 8;
    const size_t PN1_N = (size_t)15 * 8 * 8 * 64 * 8;
    const size_t PN2_N = (size_t)15 * 8 * 4 * 64 * 8;
    const size_t PEE1_N = (size_t)8 * 64 * 8;               // ee layer1 (padded)
    const size_t PEE2_N = (size_t)8 * 4 * 64 * 8;           // ee layer2
    const size_t WPK_B = (PE1_N + PE2_N + PN1_N + PN2_N + PEE1_N + PEE2_N) * 2;
    const size_t SS_B  = (size_t)NEDGES * 4;                // ssorted
    const size_t RS_B  = (size_t)NEDGES * 4;                // rsorted
    const size_t CNT_B = (size_t)NNODES * 4;                // counts
    const size_t OFF_B = (size_t)NNODES * 4;                // offsets
    const size_t CUR_B = (size_t)NNODES * 4;                // cursor
    const size_t PAR_B = 2048;                              // partials (>=391*4)
    const size_t TOTAL = AG_B + EL_B + NL_B + WPK_B + SS_B + RS_B
                       + CNT_B + OFF_B + CUR_B + PAR_B;

    if (ws_size < TOTAL) {
        float val = 1000.0f + (float)((double)ws_size * 1e-6);
        diag_kernel<<<(out_size + 255) / 256, 256, 0, stream>>>((float*)d_out, out_size, val);
        return;
    }

    char* wsp = (char*)d_ws;
    u16* aggr = (u16*)wsp;                 wsp += AG_B;
    u16* el   = (u16*)wsp;                 wsp += EL_B;
    u16* nl   = (u16*)wsp;                 wsp += NL_B;
    u16* pe1  = (u16*)wsp;                 wsp += PE1_N * 2;
    u16* pe2  = (u16*)wsp;                 wsp += PE2_N * 2;
    u16* pn1  = (u16*)wsp;                 wsp += PN1_N * 2;
    u16* pn2  = (u16*)wsp;                 wsp += PN2_N * 2;
    u16* pee1 = (u16*)wsp;                 wsp += PEE1_N * 2;
    u16* pee2 = (u16*)wsp;                 wsp += PEE2_N * 2;
    int* ssorted = (int*)wsp;              wsp += SS_B;
    int* rsorted = (int*)wsp;              wsp += RS_B;
    u32* counts  = (u32*)wsp;              wsp += CNT_B;
    u32* offsets = (u32*)wsp;              wsp += OFF_B;
    u32* cursor  = (u32*)wsp;              wsp += CUR_B;
    u32* partials = (u32*)wsp;             wsp += PAR_B;
    float* out = (float*)d_out;

    const float* pvf       = (const float*)d_in[0];
    const float* matD      = (const float*)d_in[1];
    const float* matX      = (const float*)d_in[2];
    const int*   ntype     = (const int*)d_in[3];
    const float* mesh      = (const float*)d_in[4];
    const float* world     = (const float*)d_in[5];
    const int*   senders   = (const int*)d_in[6];
    const int*   receivers = (const int*)d_in[7];
    const float* nmean = (const float*)d_in[8];
    const float* nstd  = (const float*)d_in[9];
    const float* emean = (const float*)d_in[10];
    const float* estd  = (const float*)d_in[11];
    const float* ne_w1 = (const float*)d_in[12];
    const float* ne_b1 = (const float*)d_in[13];
    const float* ne_w2 = (const float*)d_in[14];
    const float* ne_b2 = (const float*)d_in[15];
    const float* ne_g  = (const float*)d_in[16];
    const float* ne_be = (const float*)d_in[17];
    const float* ee_w1 = (const float*)d_in[18];
    const float* ee_b1 = (const float*)d_in[19];
    const float* ee_w2 = (const float*)d_in[20];
    const float* ee_b2 = (const float*)d_in[21];
    const float* ee_g  = (const float*)d_in[22];
    const float* ee_be = (const float*)d_in[23];
    const float* blk_ew1 = (const float*)d_in[24];
    const float* blk_eb1 = (const float*)d_in[25];
    const float* blk_ew2 = (const float*)d_in[26];
    const float* blk_eb2 = (const float*)d_in[27];
    const float* blk_eg  = (const float*)d_in[28];
    const float* blk_ebt = (const float*)d_in[29];
    const float* blk_nw1 = (const float*)d_in[30];
    const float* blk_nb1 = (const float*)d_in[31];
    const float* blk_nw2 = (const float*)d_in[32];
    const float* blk_nb2 = (const float*)d_in[33];
    const float* blk_ng  = (const float*)d_in[34];
    const float* blk_nbt = (const float*)d_in[35];
    const float* dec_w1 = (const float*)d_in[36];
    const float* dec_b1 = (const float*)d_in[37];
    const float* dec_w2 = (const float*)d_in[38];
    const float* dec_b2 = (const float*)d_in[39];

    // --- counting sort of edges by receiver (one-time) ---
    zero_kernel<<<(int)((CNT_B / 16 + 255) / 256), 256, 0, stream>>>((uint4*)counts, (int)(CNT_B / 16));
    count_kernel<<<(NEDGES + 255) / 256, 256, 0, stream>>>(receivers, counts);
    scan_block_kernel<<<NBSCAN, 256, 0, stream>>>(counts, offsets, partials);
    scan_partials_kernel<<<1, 512, 0, stream>>>(partials);
    add_offsets_kernel<<<NBSCAN, 256, 0, stream>>>(offsets, partials, cursor);
    scatter_kernel<<<(NEDGES + 255) / 256, 256, 0, stream>>>(senders, receivers, cursor, ssorted, rsorted);

    // pack fp16 weights into B-fragment order
    pack_weights_kernel<<<(int)((15 * 8 * 12 * 64 + 255) / 256), 256, 0, stream>>>(
        blk_ew1, pe1, 384, 15);
    pack_weights_kernel<<<(int)((15 * 8 * 4 * 64 + 255) / 256), 256, 0, stream>>>(
        blk_ew2, pe2, 128, 15);
    pack_weights_kernel<<<(int)((15 * 8 * 8 * 64 + 255) / 256), 256, 0, stream>>>(
        blk_nw1, pn1, 256, 15);
    pack_weights_kernel<<<(int)((15 * 8 * 4 * 64 + 255) / 256), 256, 0, stream>>>(
        blk_nw2, pn2, 128, 15);
    pack_ee1_kernel<<<2, 256, 0, stream>>>(ee_w1, pee1);
    pack_weights_kernel<<<(int)((8 * 4 * 64 + 255) / 256), 256, 0, stream>>>(
        ee_w2, pee2, 128, 1);

    node_encode_kernel<<<(NNODES + 63) / 64, 256, 0, stream>>>(
        pvf, matD, matX, ntype, nmean, nstd,
        ne_w1, ne_b1, ne_w2, ne_b2, ne_g, ne_be, nl);
    edge_encode_kernel<<<NEDGES / 256, 256, 0, stream>>>(
        ssorted, rsorted, pvf, mesh, world, emean, estd,
        pee1, ee_b1, pee2, ee_b2, ee_g, ee_be, el);

    // one-time aggr zero; afterwards node_block re-zeroes for the next step
    const int nzero = NNODES * L * 2 / 16;
    zero_kernel<<<(nzero + 255) / 256, 256, 0, stream>>>((uint4*)aggr, nzero);

    for (int s = 0; s < 15; s++) {
        edge_block_kernel<<<NEDGES / 256, 256, 0, stream>>>(
            ssorted, rsorted, nl, el, aggr,
            pe1 + (size_t)s * 8 * 12 * 64 * 8, blk_eb1 + s * L,
            pe2 + (size_t)s * 8 * 4 * 64 * 8,  blk_eb2 + s * L,
            blk_eg + s * L, blk_ebt + s * L);
        node_block_kernel<<<(NNODES + 255) / 256, 256, 0, stream>>>(
            nl, aggr,
            pn1 + (size_t)s * 8 * 8 * 64 * 8, blk_nb1 + s * L,
            pn2 + (size_t)s * 8 * 4 * 64 * 8, blk_nb2 + s * L,
            blk_ng + s * L, blk_nbt + s * L);
    }

    decode_kernel<<<(NNODES + 255) / 256, 256, 0, stream>>>(
        nl, dec_w1, dec_b1, dec_w2, dec_b2, out);
}